// Round 5
// baseline (389.025 us; speedup 1.0000x reference)
//
#include <hip/hip_runtime.h>
#include <hip/hip_bf16.h>

#define N_NODES 100000
#define N_EDGES 1600000
#define NFEAT 128
#define PCD 32
#define KCH 4

#define NB 391                 // ceil(N_NODES / 256) scan blocks
#define NPAD (NB * 256)        // 100,096 padded node count

// ---------------- workspace layout (bytes) ----------------
#define WS_WALLB   0           // WallB packed bf16 [8][4][64][8] -> 32,768 (pad to 64K)
#define WS_CBIAS   65536       // cbias [128] f32 -> 66,048
#define WS_P       66048       // p [N*8] f32 -> 3,266,048
#define WS_C       3266048     // c [N*128] bf16 -> 28,866,048
#define WS_RS      28866048    // row_start [NPAD] i32 -> 29,266,432
#define WS_RE      29266432    // row_end [NPAD] i32 -> 29,666,816
#define WS_CNT     29666816    // cnt [NPAD] i32 -> 30,067,200
#define WS_BSUM    30067200    // bsum [NB] i32 (pad 2048) -> 30,069,248
#define WS_BOFF    30069248    // boffs [NB] i32 (pad 2048) -> 30,071,296
#define WS_CSRCOL  30071296    // csr_col [E] i32 -> 36,471,296
#define WS_CSRW    36471296    // csr_w [E*2] u32 -> 49,271,296
// per-row cursor: aliased onto d_out's logits region (N floats, rewritten by k_agg)

typedef __attribute__((ext_vector_type(8))) short bfrag;   // 8 bf16 (4 VGPRs)
typedef __attribute__((ext_vector_type(4))) float ffrag;   // 4 f32 acc

static __device__ __forceinline__ unsigned short f2bf(float f) {
    union { float f; unsigned int u; } v; v.f = f;
    unsigned int u = v.u;
    return (unsigned short)((u + 0x7fffu + ((u >> 16) & 1u)) >> 16);  // RNE
}
static __device__ __forceinline__ float bf_lo(unsigned int u) { return __uint_as_float(u << 16); }
static __device__ __forceinline__ float bf_hi(unsigned int u) { return __uint_as_float(u & 0xffff0000u); }

// ---- fuse Wlin@Wconv -> WallB (packed B-frag bf16); cbias; zero cnt ----
__global__ void k_fuse(const float* __restrict__ Wlin, const float* __restrict__ Wconv,
                       const float* __restrict__ blin, unsigned short* __restrict__ WallB,
                       float* __restrict__ cbias, int* __restrict__ cnt) {
    int tid = blockIdx.x * 256 + threadIdx.x;
    if (tid < NPAD) cnt[tid] = 0;
    if (tid < 16384) {
        int k = tid >> 12;
        int rem = tid & 4095;
        int f = rem >> 5;          // k-index in GEMM (0..127)
        int q = rem & 31;
        float a = 0.f;
        for (int pp = 0; pp < 32; pp++)
            a += Wlin[(k * 128 + f) * 32 + pp] * Wconv[(k * 32 + pp) * 32 + q];
        int col = k * 32 + q;      // n-index (0..127)
        // packed B-fragment layout for mfma_f32_16x16x32_bf16:
        // lane = (klocal>>3)*16 + (col&15), j = klocal&7, klocal = f&31, kstep = f>>5
        int ntile = col >> 4, n15 = col & 15;
        int kstep = f >> 5, kl = f & 31;
        int lane = (kl >> 3) * 16 + n15;
        int j = kl & 7;
        WallB[(((ntile * 4 + kstep) * 64 + lane) << 3) + j] = f2bf(a);
    } else if (tid < 16512) {
        int i = tid - 16384;
        int k = i >> 5;
        int q = i & 31;
        float a = 0.f;
        for (int pp = 0; pp < 32; pp++)
            a += blin[k * 32 + pp] * Wconv[(k * 32 + pp) * 32 + q];
        cbias[k * 32 + q] = a;
    }
}

// ---- c[N,128] = bf16(x @ Wall + cbias) via MFMA;  p[N,8] = x @ aW1 (epilogue) ----
#define XLD 136   // bf16 elements per LDS row (16B-aligned frag reads)
__global__ __launch_bounds__(256) void k_cgemm(const float* __restrict__ x,
                                               const unsigned short* __restrict__ WallB,
                                               const float* __restrict__ cbias,
                                               const float* __restrict__ aW1,
                                               unsigned short* __restrict__ c,
                                               float* __restrict__ p) {
    __shared__ unsigned short xs[64 * XLD];   // 17,408 B (bf16 x-tile)
    __shared__ float aT[8 * 132];             // 4,224 B
    int t = threadIdx.x;
    int row0 = blockIdx.x * 64;
    int wv = t >> 6;
    int lane = t & 63;

    // stage aW1 transposed (fp32)
    for (int i = t; i < 1024; i += 256) {
        int j = i >> 7;
        int f = i & 127;
        float v = (j < 4) ? aW1[f * 4 + j] : aW1[512 + f * 4 + (j - 4)];
        aT[j * 132 + f] = v;
    }

    // stage 64 x-rows -> bf16 LDS
    const float4* xg = (const float4*)(x + (size_t)row0 * 128);
    for (int i = 0; i < 8; i++) {
        int idx = i * 256 + t;           // float4 index, 0..2047
        int r = idx >> 5;
        int cc = idx & 31;
        float4 v = make_float4(0.f, 0.f, 0.f, 0.f);
        if (row0 + r < N_NODES) v = xg[idx];
        ushort4 o;
        o.x = f2bf(v.x); o.y = f2bf(v.y); o.z = f2bf(v.z); o.w = f2bf(v.w);
        *(ushort4*)(xs + r * XLD + cc * 4) = o;
    }
    __syncthreads();

    // B fragments: wave wv owns cols [wv*32, wv*32+32) -> ntiles wv*2, wv*2+1
    bfrag B[2][4];
    #pragma unroll
    for (int nn = 0; nn < 2; nn++)
        #pragma unroll
        for (int ks = 0; ks < 4; ks++)
            B[nn][ks] = *(const bfrag*)(WallB + ((((wv * 2 + nn) * 4 + ks) * 64 + lane) << 3));

    ffrag acc[4][2];
    #pragma unroll
    for (int m = 0; m < 4; m++)
        #pragma unroll
        for (int nn = 0; nn < 2; nn++)
            acc[m][nn] = (ffrag){0.f, 0.f, 0.f, 0.f};

    int mrow = lane & 15;
    int koff = (lane >> 4) * 8;

    #pragma unroll
    for (int ks = 0; ks < 4; ks++) {
        bfrag A[4];
        #pragma unroll
        for (int m = 0; m < 4; m++)
            A[m] = *(const bfrag*)(xs + (m * 16 + mrow) * XLD + ks * 32 + koff);
        #pragma unroll
        for (int m = 0; m < 4; m++)
            #pragma unroll
            for (int nn = 0; nn < 2; nn++)
                acc[m][nn] = __builtin_amdgcn_mfma_f32_16x16x32_bf16(A[m], B[nn][ks], acc[m][nn], 0, 0, 0);
    }

    // epilogue: D[row = mtile*16 + quad*4 + r][col = wv*32 + nn*16 + (lane&15)]
    int quad = lane >> 4;
    int coln = lane & 15;
    #pragma unroll
    for (int nn = 0; nn < 2; nn++) {
        int col = wv * 32 + nn * 16 + coln;
        float cb = cbias[col];
        #pragma unroll
        for (int m = 0; m < 4; m++) {
            #pragma unroll
            for (int r = 0; r < 4; r++) {
                int row = row0 + m * 16 + quad * 4 + r;
                if (row < N_NODES)
                    c[(size_t)row * 128 + col] = f2bf(acc[m][nn][r] + cb);
            }
        }
    }

    // p epilogue (bf16 xs)
    int j = t & 7;
    const float* arow = aT + j * 132;
    for (int pass = 0; pass < 2; pass++) {
        int r = (t >> 3) + pass * 32;
        const unsigned int* xrow = (const unsigned int*)(xs + r * XLD);
        float accp = 0.f;
        #pragma unroll 8
        for (int f2 = 0; f2 < 64; f2++) {
            unsigned int u = xrow[f2];
            accp += bf_lo(u) * arow[2 * f2] + bf_hi(u) * arow[2 * f2 + 1];
        }
        int row = row0 + r;
        if (row < N_NODES) p[(size_t)row * 8 + j] = accp;
    }
}

// ---- histogram of edge rows (int4-vectorized) ----
__global__ __launch_bounds__(256) void k_hist(const int4* __restrict__ erow4,
                                              int* __restrict__ cnt) {
    int i = blockIdx.x * 256 + threadIdx.x;
    if (i < N_EDGES / 4) {
        int4 v = erow4[i];
        atomicAdd(&cnt[v.x], 1);
        atomicAdd(&cnt[v.y], 1);
        atomicAdd(&cnt[v.z], 1);
        atomicAdd(&cnt[v.w], 1);
    }
}

// ---- scan stage 1: per-256-block exclusive scan + block sums ----
__global__ __launch_bounds__(256) void k_scan1(const int* __restrict__ cnt,
                                               int* __restrict__ row_start,
                                               int* __restrict__ bsum) {
    __shared__ int wtot[4];
    int b = blockIdx.x;
    int t = threadIdx.x;
    int i = b * 256 + t;
    int v = cnt[i];                   // cnt padded & zeroed to NPAD
    int s = v;
    #pragma unroll
    for (int d = 1; d < 64; d <<= 1) {
        int u = __shfl_up(s, d);
        if ((t & 63) >= d) s += u;
    }
    if ((t & 63) == 63) wtot[t >> 6] = s;
    __syncthreads();
    int add = 0;
    for (int w = 0; w < (t >> 6); w++) add += wtot[w];
    row_start[i] = s - v + add;       // block-local exclusive prefix
    if (t == 255) bsum[b] = s + add;  // block total
}

// ---- scan stage 2: single-wave scan of NB block sums ----
__global__ __launch_bounds__(64) void k_scan2(const int* __restrict__ bsum,
                                              int* __restrict__ boffs) {
    int t = threadIdx.x;
    int carry = 0;
    for (int ck = 0; ck < (NB + 63) / 64; ck++) {
        int i = ck * 64 + t;
        int v = (i < NB) ? bsum[i] : 0;
        int s = v;
        #pragma unroll
        for (int d = 1; d < 64; d <<= 1) {
            int u = __shfl_up(s, d);
            if (t >= d) s += u;
        }
        if (i < NB) boffs[i] = s - v + carry;
        carry += __shfl(s, 63);
    }
}

// ---- scan stage 3: global offsets; init row_start/row_end/rowcur ----
__global__ __launch_bounds__(256) void k_scan3(const int* __restrict__ cnt,
                                               const int* __restrict__ boffs,
                                               int* __restrict__ row_start,
                                               int* __restrict__ row_end,
                                               int* __restrict__ rowcur) {
    int i = blockIdx.x * 256 + threadIdx.x;
    if (i < N_NODES) {
        int st = row_start[i] + boffs[i >> 8];
        row_start[i] = st;
        row_end[i] = st + cnt[i];
        rowcur[i] = st;
    }
}

// ---- softmax + direct CSR fill from raw edge list ----
__global__ __launch_bounds__(256) void k_fill(const int* __restrict__ erow,
                                              const int* __restrict__ ecol,
                                              const float* __restrict__ p,
                                              const float* __restrict__ aW2,
                                              const float* __restrict__ ab1,
                                              const float* __restrict__ ab2,
                                              int* __restrict__ rowcur,
                                              int* __restrict__ csr_col,
                                              unsigned int* __restrict__ csr_w) {
    int e = blockIdx.x * 256 + threadIdx.x;
    if (e >= N_EDGES) return;
    int r = erow[e];
    int cl = ecol[e];
    float4 pc = *(const float4*)(p + (size_t)cl * 8);
    float4 prr = *(const float4*)(p + (size_t)r * 8 + 4);
    float h0 = pc.x + prr.x + ab1[0];
    float h1 = pc.y + prr.y + ab1[1];
    float h2 = pc.z + prr.z + ab1[2];
    float h3 = pc.w + prr.w + ab1[3];
    float sc[4];
    #pragma unroll
    for (int jq = 0; jq < 4; jq++)
        sc[jq] = h0 * aW2[jq] + h1 * aW2[4 + jq] + h2 * aW2[8 + jq] + h3 * aW2[12 + jq] + ab2[jq];
    float m = fmaxf(fmaxf(sc[0], sc[1]), fmaxf(sc[2], sc[3]));
    float e0 = expf(sc[0] - m), e1 = expf(sc[1] - m), e2 = expf(sc[2] - m), e3 = expf(sc[3] - m);
    float inv = 1.f / (e0 + e1 + e2 + e3);
    unsigned int w01 = (unsigned int)f2bf(e0 * inv) | ((unsigned int)f2bf(e1 * inv) << 16);
    unsigned int w23 = (unsigned int)f2bf(e2 * inv) | ((unsigned int)f2bf(e3 * inv) << 16);
    int pos = atomicAdd(&rowcur[r], 1);
    csr_col[pos] = cl;
    uint2 wp; wp.x = w01; wp.y = w23;
    *(uint2*)(csr_w + (size_t)pos * 2) = wp;
}

// ---- aggregation: one wave per node; register-preloaded col/w segment + ----
// ---- shfl-broadcast addresses -> dependency-free batched gathers ----
template<int M, bool MASKED>
static __device__ __forceinline__ void agg_chunk(const unsigned int* __restrict__ c4,
                                                 int q, int cnt, int colv, unsigned int wvv,
                                                 int pair5, int lane, int wshl,
                                                 float& acc0, float& acc1) {
    unsigned int u[M], wq[M], addr[M];
    #pragma unroll
    for (int k = 0; k < M; k++) {
        int qq = q + k;
        bool val = !MASKED || (qq < cnt);
        int srcl = (val ? qq : q) | pair5;
        int cq = __shfl(colv, srcl);
        unsigned int ww = (unsigned int)__shfl((int)wvv, srcl);
        wq[k] = val ? ww : 0u;
        addr[k] = ((unsigned int)cq << 6) | (unsigned int)lane;
    }
    #pragma unroll
    for (int k = 0; k < M; k++) u[k] = c4[addr[k]];
    #pragma unroll
    for (int k = 0; k < M; k++) {
        float w = __uint_as_float((wq[k] << wshl) & 0xffff0000u);
        acc0 += w * bf_lo(u[k]);
        acc1 += w * bf_hi(u[k]);
    }
}

__global__ __launch_bounds__(256, 8) void k_agg(const int* __restrict__ csr_col,
                                                const unsigned int* __restrict__ csr_w,
                                                const unsigned int* __restrict__ c4,
                                                const int* __restrict__ row_start,
                                                const int* __restrict__ row_end,
                                                const float* __restrict__ bch,
                                                const float* __restrict__ Wcls,
                                                const float* __restrict__ bcls,
                                                float* __restrict__ out) {
    int n = (blockIdx.x * 256 + threadIdx.x) >> 6;
    int lane = threadIdx.x & 63;
    if (n >= N_NODES) return;
    int ch = lane >> 4;              // channel of both features 2*lane, 2*lane+1
    int pair5 = lane & 32;           // 0 -> w01 holder lanes, 32 -> w23 holder lanes
    int wshl = (ch & 1) ? 0 : 16;    // even channel sits in low half -> <<16
    int f0 = 2 * lane, f1 = 2 * lane + 1;

    int start = __builtin_amdgcn_readfirstlane(row_start[n]);
    int end = __builtin_amdgcn_readfirstlane(row_end[n]);

    float acc0 = 0.f, acc1 = 0.f;

    for (int s0 = start; s0 < end; s0 += 32) {
        int cnt = end - s0; if (cnt > 32) cnt = 32;
        // preload segment: lane e (mod 32) holds col of edge s0+e (both halves);
        // lanes 0-31 hold w01 word, lanes 32-63 hold w23 word of the same edge
        int e = s0 + (lane & 31);
        int ec = (e < end) ? e : (end - 1);
        int colv = csr_col[ec];
        unsigned int wvv = csr_w[((size_t)ec << 1) + (lane >> 5)];

        int q = 0;
        for (; q + 8 <= cnt; q += 8)
            agg_chunk<8, false>(c4, q, cnt, colv, wvv, pair5, lane, wshl, acc0, acc1);
        int rem = cnt - q;
        if (rem > 4)
            agg_chunk<8, true>(c4, q, cnt, colv, wvv, pair5, lane, wshl, acc0, acc1);
        else if (rem > 0)
            agg_chunk<4, true>(c4, q, cnt, colv, wvv, pair5, lane, wshl, acc0, acc1);
    }

    float v0 = acc0 + bch[f0];
    float v1 = acc1 + bch[f1];

    // per-channel L2 norm: channel = 16 consecutive lanes
    float ss = v0 * v0 + v1 * v1;
    #pragma unroll
    for (int m = 1; m <= 8; m <<= 1) ss += __shfl_xor(ss, m);
    float inv = 1.f / fmaxf(sqrtf(ss), 1e-12f);
    v0 *= inv;
    v1 *= inv;

    *(float2*)(out + (size_t)n * 128 + f0) = make_float2(v0, v1);

    float pl = v0 * Wcls[f0] + v1 * Wcls[f1];
    #pragma unroll
    for (int m = 1; m <= 32; m <<= 1) pl += __shfl_xor(pl, m);
    if (lane == 0) out[(size_t)N_NODES * 128 + n] = pl + bcls[0];
}

extern "C" void kernel_launch(void* const* d_in, const int* in_sizes, int n_in,
                              void* d_out, int out_size, void* d_ws, size_t ws_size,
                              hipStream_t stream) {
    const float* x    = (const float*)d_in[0];
    const int*   erow = (const int*)d_in[1];
    const int*   ecol = (const int*)d_in[2];
    const float* aW1  = (const float*)d_in[3];
    const float* ab1  = (const float*)d_in[4];
    const float* aW2  = (const float*)d_in[5];
    const float* ab2  = (const float*)d_in[6];
    const float* Wlin = (const float*)d_in[7];
    const float* blin = (const float*)d_in[8];
    const float* Wconv= (const float*)d_in[9];
    const float* bch  = (const float*)d_in[10];
    const float* Wcls = (const float*)d_in[11];
    const float* bcls = (const float*)d_in[12];
    float* out = (float*)d_out;

    char* ws = (char*)d_ws;
    unsigned short* WallB   = (unsigned short*)(ws + WS_WALLB);
    float*          cbias   = (float*)(ws + WS_CBIAS);
    float*          p       = (float*)(ws + WS_P);
    unsigned short* c       = (unsigned short*)(ws + WS_C);
    int*            rstart  = (int*)(ws + WS_RS);
    int*            rend    = (int*)(ws + WS_RE);
    int*            cnt     = (int*)(ws + WS_CNT);
    int*            bsum    = (int*)(ws + WS_BSUM);
    int*            boffs   = (int*)(ws + WS_BOFF);
    int*            csr_col = (int*)(ws + WS_CSRCOL);
    unsigned int*   csr_w   = (unsigned int*)(ws + WS_CSRW);
    int*            rowcur  = (int*)(out + (size_t)N_NODES * 128);

    k_fuse<<<NB, 256, 0, stream>>>(Wlin, Wconv, blin, WallB, cbias, cnt);
    k_cgemm<<<(N_NODES + 63) / 64, 256, 0, stream>>>(x, WallB, cbias, aW1, c, p);
    k_hist<<<(N_EDGES / 4 + 255) / 256, 256, 0, stream>>>((const int4*)erow, cnt);
    k_scan1<<<NB, 256, 0, stream>>>(cnt, rstart, bsum);
    k_scan2<<<1, 64, 0, stream>>>(bsum, boffs);
    k_scan3<<<NB, 256, 0, stream>>>(cnt, boffs, rstart, rend, rowcur);
    k_fill<<<(N_EDGES + 255) / 256, 256, 0, stream>>>(erow, ecol, p, aW2, ab1, ab2,
                                                      rowcur, csr_col, csr_w);
    k_agg<<<(N_NODES * 64 + 255) / 256, 256, 0, stream>>>(csr_col, csr_w, (const unsigned int*)c,
                                                          rstart, rend, bch, Wcls, bcls, out);
}

// Round 6
// 287.605 us; speedup vs baseline: 1.3526x; 1.3526x over previous
//
#include <hip/hip_runtime.h>
#include <hip/hip_bf16.h>

#define N_NODES 100000
#define N_EDGES 1600000
#define NFEAT 128
#define PCD 32
#define KCH 4

#define TILE_E 4096
#define T_TILES 391            // ceil(N_EDGES / TILE_E)
#define BSH 8
#define NB 391                 // ceil(N_NODES / 256)
#define CAP 5120               // per-bucket capacity (mean 4096, +16 sigma)
#define NCAP (NB * CAP)        // 2,001,920
#define CAPQ 1408              // per-64-row quarter capacity (mean 1024, +12 sigma)

// ---------------- workspace layout (bytes) ----------------
#define WS_WALLB   0           // WallB packed bf16 [8][4][64][8] -> 32,768
#define WS_CBIAS   65536       // cbias [128] f32 -> 66,048
#define WS_P       66048       // p [N*8] f32 -> 3,266,048
#define WS_C       3266048     // c [N*128] bf16 -> 28,866,048
#define WS_CUR     29666048    // gcursor [NB] i32 -> 29,667,840 (padded)
#define WS_BUCK    29667840    // bucketed [NCAP] uint2 -> 45,683,200

typedef __attribute__((ext_vector_type(8))) short bfrag;   // 8 bf16 (4 VGPRs)
typedef __attribute__((ext_vector_type(4))) float ffrag;   // 4 f32 acc

static __device__ __forceinline__ unsigned short f2bf(float f) {
    union { float f; unsigned int u; } v; v.f = f;
    unsigned int u = v.u;
    return (unsigned short)((u + 0x7fffu + ((u >> 16) & 1u)) >> 16);  // RNE
}
static __device__ __forceinline__ float bf_lo(unsigned int u) { return __uint_as_float(u << 16); }
static __device__ __forceinline__ float bf_hi(unsigned int u) { return __uint_as_float(u & 0xffff0000u); }

// ---- fuse Wlin@Wconv -> WallB (packed B-frag bf16); cbias; init gcursor ----
__global__ void k_fuse(const float* __restrict__ Wlin, const float* __restrict__ Wconv,
                       const float* __restrict__ blin, unsigned short* __restrict__ WallB,
                       float* __restrict__ cbias, int* __restrict__ gcursor) {
    int tid = blockIdx.x * 256 + threadIdx.x;
    if (tid < 16384) {
        int k = tid >> 12;
        int rem = tid & 4095;
        int f = rem >> 5;          // k-index in GEMM (0..127)
        int q = rem & 31;
        float a = 0.f;
        for (int pp = 0; pp < 32; pp++)
            a += Wlin[(k * 128 + f) * 32 + pp] * Wconv[(k * 32 + pp) * 32 + q];
        int col = k * 32 + q;      // n-index (0..127)
        int ntile = col >> 4, n15 = col & 15;
        int kstep = f >> 5, kl = f & 31;
        int lane = (kl >> 3) * 16 + n15;
        int j = kl & 7;
        WallB[(((ntile * 4 + kstep) * 64 + lane) << 3) + j] = f2bf(a);
    } else if (tid < 16512) {
        int i = tid - 16384;
        int k = i >> 5;
        int q = i & 31;
        float a = 0.f;
        for (int pp = 0; pp < 32; pp++)
            a += blin[k * 32 + pp] * Wconv[(k * 32 + pp) * 32 + q];
        cbias[k * 32 + q] = a;
    } else if (tid - 16512 < NB) {
        gcursor[tid - 16512] = (tid - 16512) * CAP;
    }
}

// ---- c[N,128] = bf16(x @ Wall + cbias) via MFMA;  p[N,8] = x @ aW1 (epilogue) ----
#define XLD 136   // bf16 elements per LDS row (16B-aligned frag reads)
__global__ __launch_bounds__(256) void k_cgemm(const float* __restrict__ x,
                                               const unsigned short* __restrict__ WallB,
                                               const float* __restrict__ cbias,
                                               const float* __restrict__ aW1,
                                               unsigned short* __restrict__ c,
                                               float* __restrict__ p) {
    __shared__ unsigned short xs[64 * XLD];   // 17,408 B (bf16 x-tile)
    __shared__ float aT[8 * 132];             // 4,224 B
    int t = threadIdx.x;
    int row0 = blockIdx.x * 64;
    int wv = t >> 6;
    int lane = t & 63;

    // stage aW1 transposed (fp32)
    for (int i = t; i < 1024; i += 256) {
        int j = i >> 7;
        int f = i & 127;
        float v = (j < 4) ? aW1[f * 4 + j] : aW1[512 + f * 4 + (j - 4)];
        aT[j * 132 + f] = v;
    }

    // stage 64 x-rows -> bf16 LDS
    const float4* xg = (const float4*)(x + (size_t)row0 * 128);
    for (int i = 0; i < 8; i++) {
        int idx = i * 256 + t;           // float4 index, 0..2047
        int r = idx >> 5;
        int cc = idx & 31;
        float4 v = make_float4(0.f, 0.f, 0.f, 0.f);
        if (row0 + r < N_NODES) v = xg[idx];
        ushort4 o;
        o.x = f2bf(v.x); o.y = f2bf(v.y); o.z = f2bf(v.z); o.w = f2bf(v.w);
        *(ushort4*)(xs + r * XLD + cc * 4) = o;
    }
    __syncthreads();

    // B fragments: wave wv owns cols [wv*32, wv*32+32) -> ntiles wv*2, wv*2+1
    bfrag B[2][4];
    #pragma unroll
    for (int nn = 0; nn < 2; nn++)
        #pragma unroll
        for (int ks = 0; ks < 4; ks++)
            B[nn][ks] = *(const bfrag*)(WallB + ((((wv * 2 + nn) * 4 + ks) * 64 + lane) << 3));

    ffrag acc[4][2];
    #pragma unroll
    for (int m = 0; m < 4; m++)
        #pragma unroll
        for (int nn = 0; nn < 2; nn++)
            acc[m][nn] = (ffrag){0.f, 0.f, 0.f, 0.f};

    int mrow = lane & 15;
    int koff = (lane >> 4) * 8;

    #pragma unroll
    for (int ks = 0; ks < 4; ks++) {
        bfrag A[4];
        #pragma unroll
        for (int m = 0; m < 4; m++)
            A[m] = *(const bfrag*)(xs + (m * 16 + mrow) * XLD + ks * 32 + koff);
        #pragma unroll
        for (int m = 0; m < 4; m++)
            #pragma unroll
            for (int nn = 0; nn < 2; nn++)
                acc[m][nn] = __builtin_amdgcn_mfma_f32_16x16x32_bf16(A[m], B[nn][ks], acc[m][nn], 0, 0, 0);
    }

    // epilogue: D[row = mtile*16 + quad*4 + r][col = wv*32 + nn*16 + (lane&15)]
    int quad = lane >> 4;
    int coln = lane & 15;
    #pragma unroll
    for (int nn = 0; nn < 2; nn++) {
        int col = wv * 32 + nn * 16 + coln;
        float cb = cbias[col];
        #pragma unroll
        for (int m = 0; m < 4; m++) {
            #pragma unroll
            for (int r = 0; r < 4; r++) {
                int row = row0 + m * 16 + quad * 4 + r;
                if (row < N_NODES)
                    c[(size_t)row * 128 + col] = f2bf(acc[m][nn][r] + cb);
            }
        }
    }

    // p epilogue (bf16 xs)
    int j = t & 7;
    const float* arow = aT + j * 132;
    for (int pass = 0; pass < 2; pass++) {
        int r = (t >> 3) + pass * 32;
        const unsigned int* xrow = (const unsigned int*)(xs + r * XLD);
        float accp = 0.f;
        #pragma unroll 8
        for (int f2 = 0; f2 < 64; f2++) {
            unsigned int u = xrow[f2];
            accp += bf_lo(u) * arow[2 * f2] + bf_hi(u) * arow[2 * f2 + 1];
        }
        int row = row0 + r;
        if (row < N_NODES) p[(size_t)row * 8 + j] = accp;
    }
}

// ---- bucket scatter (512 thr): LDS-reorder tile by bucket, claim runs, copy out ----
__global__ __launch_bounds__(512) void k_bucket_scatter(const int* __restrict__ erow,
                                                        const int* __restrict__ ecol,
                                                        int* __restrict__ gcursor,
                                                        uint2* __restrict__ bucketed) {
    __shared__ int lcnt[NB];
    __shared__ int lstart[NB];
    __shared__ int lcur[NB];
    __shared__ int gbase[NB];
    __shared__ uint2 buf[TILE_E];
    int t = threadIdx.x;
    int tile = blockIdx.x;
    int base = tile * TILE_E;
    int cnt = N_EDGES - base; if (cnt > TILE_E) cnt = TILE_E;

    for (int i = t; i < NB; i += 512) lcnt[i] = 0;
    __syncthreads();

    int rows[TILE_E / 512], cols[TILE_E / 512];
    #pragma unroll
    for (int i = 0; i < TILE_E / 512; i++) {
        int e = base + i * 512 + t;
        if (e < N_EDGES) {
            rows[i] = erow[e];
            cols[i] = ecol[e];
            atomicAdd(&lcnt[rows[i] >> BSH], 1);
        } else rows[i] = -1;
    }
    __syncthreads();

    if (t < 64) {
        int carry = 0;
        for (int ck = 0; ck < (NB + 63) / 64; ck++) {
            int i = ck * 64 + t;
            int v = (i < NB) ? lcnt[i] : 0;
            int s = v;
            #pragma unroll
            for (int d = 1; d < 64; d <<= 1) {
                int u = __shfl_up(s, d);
                if (t >= d) s += u;
            }
            int excl = s - v + carry;
            if (i < NB) { lstart[i] = excl; lcur[i] = excl; }
            carry += __shfl(s, 63);
        }
    } else {
        for (int i = t - 64; i < NB; i += 448)
            gbase[i] = atomicAdd(&gcursor[i], lcnt[i]);
    }
    __syncthreads();

    #pragma unroll
    for (int i = 0; i < TILE_E / 512; i++) {
        if (rows[i] >= 0) {
            int b = rows[i] >> BSH;
            int pos = atomicAdd(&lcur[b], 1);
            buf[pos] = make_uint2((unsigned)rows[i], (unsigned)cols[i]);
        }
    }
    __syncthreads();

    for (int jj = t; jj < cnt; jj += 512) {
        uint2 pr = buf[jj];
        int b = (int)pr.x >> BSH;
        int gpos = gbase[b] + (jj - lstart[b]);
        bucketed[gpos] = pr;
    }
}

// ---- fused: LDS row-sort + softmax + gather-aggregate + norm + classify ----
// Block = 64 rows (quarter of a 256-row parent bucket). Scans the parent
// bucket's records (L2-shared with 3 sibling blocks), histograms its rows,
// computes softmax weights in-pass, fills a row-sorted LDS record array,
// then 4 waves x 16 rows do the 8-deep dependency-free c-gather accumulate
// and write normalized output + logits directly. No global fine-CSR.
template<int M, bool MASKED>
static __device__ __forceinline__ void chunkB(const uint4* __restrict__ edata,
                                              int k, int en,
                                              const unsigned int* __restrict__ c4,
                                              int lane, int pair, int wshl,
                                              float& acc0, float& acc1) {
    unsigned int u[M], ws[M], ad[M];
    #pragma unroll
    for (int j = 0; j < M; j++) {
        int kk = k + j;
        bool val = !MASKED || (kk < en);
        uint4 rec = edata[val ? kk : k];
        unsigned int wsel = pair ? rec.z : rec.y;
        ws[j] = val ? ((wsel << wshl) & 0xffff0000u) : 0u;
        ad[j] = (rec.x << 6) | (unsigned int)lane;
    }
    #pragma unroll
    for (int j = 0; j < M; j++) u[j] = c4[ad[j]];
    #pragma unroll
    for (int j = 0; j < M; j++) {
        float w = __uint_as_float(ws[j]);
        acc0 += w * bf_lo(u[j]);
        acc1 += w * bf_hi(u[j]);
    }
}

__global__ __launch_bounds__(256) void k_aggfuse(const uint2* __restrict__ bucketed,
                                                 const int* __restrict__ gcursor,
                                                 const float* __restrict__ p,
                                                 const float* __restrict__ aW2,
                                                 const float* __restrict__ ab1,
                                                 const float* __restrict__ ab2,
                                                 const unsigned int* __restrict__ c4,
                                                 const float* __restrict__ bch,
                                                 const float* __restrict__ Wcls,
                                                 const float* __restrict__ bcls,
                                                 float* __restrict__ out) {
    __shared__ uint4 edata[CAPQ];          // 22,528 B  (col, w01, w23, 0)
    __shared__ float prr[64][4];           // 1,024 B   p[row][4..8)
    __shared__ int hist[64];
    __shared__ int rstart[64];
    __shared__ int rcur[64];
    __shared__ float sab1[4], sab2[4], saW2[16];

    int t = threadIdx.x;
    int n0 = blockIdx.x * 64;              // first row of my 64-row slice
    int b8 = blockIdx.x >> 2;              // parent bucket
    int bstart = b8 * CAP;
    int bend = gcursor[b8];                // absolute end (init was b8*CAP)

    if (t < 64) { hist[t] = 0; rcur[t] = 0; }
    if (t < 4)  { sab1[t] = ab1[t]; sab2[t] = ab2[t]; }
    if (t >= 64 && t < 80) saW2[t - 64] = aW2[t - 64];
    if (t >= 128 && t < 192) {
        int n = n0 + (t - 128);
        float4 pv = make_float4(0.f, 0.f, 0.f, 0.f);
        if (n < N_NODES) pv = *(const float4*)(p + (size_t)n * 8 + 4);
        *(float4*)prr[t - 128] = pv;
    }
    __syncthreads();

    // pass 1: histogram my rows over the parent bucket's records
    for (int i = bstart + t; i < bend; i += 256) {
        int rl = (int)bucketed[i].x - n0;
        if ((unsigned)rl < 64u) atomicAdd(&hist[rl], 1);
    }
    __syncthreads();

    // exclusive scan of 64 bins (wave 0)
    if (t < 64) {
        int v = hist[t];
        int s = v;
        #pragma unroll
        for (int d = 1; d < 64; d <<= 1) {
            int u = __shfl_up(s, d);
            if (t >= d) s += u;
        }
        rstart[t] = s - v;
    }
    __syncthreads();

    // pass 2: softmax weights + row-sorted fill of edata
    for (int i = bstart + t; i < bend; i += 256) {
        uint2 rc = bucketed[i];
        int rl = (int)rc.x - n0;
        if ((unsigned)rl < 64u) {
            int cl = (int)rc.y;
            float4 pc = *(const float4*)(p + (size_t)cl * 8);
            float h0 = pc.x + prr[rl][0] + sab1[0];
            float h1 = pc.y + prr[rl][1] + sab1[1];
            float h2 = pc.z + prr[rl][2] + sab1[2];
            float h3 = pc.w + prr[rl][3] + sab1[3];
            float sc[4];
            #pragma unroll
            for (int jq = 0; jq < 4; jq++)
                sc[jq] = h0 * saW2[jq] + h1 * saW2[4 + jq] + h2 * saW2[8 + jq]
                       + h3 * saW2[12 + jq] + sab2[jq];
            float m = fmaxf(fmaxf(sc[0], sc[1]), fmaxf(sc[2], sc[3]));
            float e0 = expf(sc[0] - m), e1 = expf(sc[1] - m);
            float e2 = expf(sc[2] - m), e3 = expf(sc[3] - m);
            float inv = 1.f / (e0 + e1 + e2 + e3);
            unsigned int w01 = (unsigned int)f2bf(e0 * inv) | ((unsigned int)f2bf(e1 * inv) << 16);
            unsigned int w23 = (unsigned int)f2bf(e2 * inv) | ((unsigned int)f2bf(e3 * inv) << 16);
            int pos = rstart[rl] + atomicAdd(&rcur[rl], 1);
            edata[pos] = make_uint4((unsigned int)cl, w01, w23, 0u);
        }
    }
    __syncthreads();

    // phase B: 4 waves x 16 rows, register accumulate + direct epilogue
    int wv = t >> 6;
    int lane = t & 63;
    int ch = lane >> 4;
    int pair = ch >> 1;
    int wshl = (ch & 1) ? 0 : 16;
    int f0 = 2 * lane, f1 = f0 + 1;
    float bch0 = bch[f0], bch1 = bch[f1];
    float wc0 = Wcls[f0], wc1 = Wcls[f1];
    float bc = bcls[0];

    for (int r16 = 0; r16 < 16; r16++) {
        int rl = wv * 16 + r16;
        int n = n0 + rl;
        if (n >= N_NODES) continue;
        int st = __builtin_amdgcn_readfirstlane(rstart[rl]);
        int en = __builtin_amdgcn_readfirstlane(rstart[rl] + hist[rl]);

        float acc0 = 0.f, acc1 = 0.f;
        int k = st;
        for (; k + 8 <= en; k += 8)
            chunkB<8, false>(edata, k, en, c4, lane, pair, wshl, acc0, acc1);
        int rem = en - k;
        if (rem > 4)
            chunkB<8, true>(edata, k, en, c4, lane, pair, wshl, acc0, acc1);
        else if (rem > 0)
            chunkB<4, true>(edata, k, en, c4, lane, pair, wshl, acc0, acc1);

        float v0 = acc0 + bch0;
        float v1 = acc1 + bch1;
        float ss = v0 * v0 + v1 * v1;
        #pragma unroll
        for (int m = 1; m <= 8; m <<= 1) ss += __shfl_xor(ss, m);
        float inv = 1.f / fmaxf(sqrtf(ss), 1e-12f);
        v0 *= inv;
        v1 *= inv;

        *(float2*)(out + (size_t)n * 128 + f0) = make_float2(v0, v1);

        float pl = v0 * wc0 + v1 * wc1;
        #pragma unroll
        for (int m = 1; m <= 32; m <<= 1) pl += __shfl_xor(pl, m);
        if (lane == 0) out[(size_t)N_NODES * 128 + n] = pl + bc;
    }
}

extern "C" void kernel_launch(void* const* d_in, const int* in_sizes, int n_in,
                              void* d_out, int out_size, void* d_ws, size_t ws_size,
                              hipStream_t stream) {
    const float* x    = (const float*)d_in[0];
    const int*   erow = (const int*)d_in[1];
    const int*   ecol = (const int*)d_in[2];
    const float* aW1  = (const float*)d_in[3];
    const float* ab1  = (const float*)d_in[4];
    const float* aW2  = (const float*)d_in[5];
    const float* ab2  = (const float*)d_in[6];
    const float* Wlin = (const float*)d_in[7];
    const float* blin = (const float*)d_in[8];
    const float* Wconv= (const float*)d_in[9];
    const float* bch  = (const float*)d_in[10];
    const float* Wcls = (const float*)d_in[11];
    const float* bcls = (const float*)d_in[12];
    float* out = (float*)d_out;

    char* ws = (char*)d_ws;
    unsigned short* WallB   = (unsigned short*)(ws + WS_WALLB);
    float*          cbias   = (float*)(ws + WS_CBIAS);
    float*          p       = (float*)(ws + WS_P);
    unsigned short* c       = (unsigned short*)(ws + WS_C);
    int*            gcursor = (int*)(ws + WS_CUR);
    uint2*          bucketed= (uint2*)(ws + WS_BUCK);

    k_fuse<<<67, 256, 0, stream>>>(Wlin, Wconv, blin, WallB, cbias, gcursor);
    k_cgemm<<<(N_NODES + 63) / 64, 256, 0, stream>>>(x, WallB, cbias, aW1, c, p);
    k_bucket_scatter<<<T_TILES, 512, 0, stream>>>(erow, ecol, gcursor, bucketed);
    k_aggfuse<<<(N_NODES + 63) / 64, 256, 0, stream>>>(bucketed, gcursor, p, aW2, ab1, ab2,
                                                       (const unsigned int*)c, bch, Wcls, bcls, out);
}

// Round 7
// 262.459 us; speedup vs baseline: 1.4822x; 1.0958x over previous
//
#include <hip/hip_runtime.h>
#include <hip/hip_bf16.h>

#define N_NODES 100000
#define N_EDGES 1600000
#define NFEAT 128
#define PCD 32
#define KCH 4

#define TILE_E 4096
#define T_TILES 391            // ceil(N_EDGES / TILE_E)
#define BSH 8
#define NB 391                 // ceil(N_NODES / 256)
#define CAP 5120               // per-bucket capacity (mean 4096, +16 sigma)
#define NCAP (NB * CAP)        // 2,001,920

// ---------------- workspace layout (bytes) ----------------
#define WS_WALLB   0           // WallB packed bf16 [8][4][64][8] -> 32,768
#define WS_CBIAS   65536       // cbias [128] f32 -> 66,048
#define WS_P       66048       // p [N*8] f32 -> 3,266,048
#define WS_C       3266048     // c [N*128] bf16 -> 28,866,048
#define WS_RS      28866048    // row_start [N] i32 -> 29,266,048
#define WS_RE      29266048    // row_end [N] i32 -> 29,666,048
#define WS_CUR     29666048    // gcursor [NB] i32 -> 29,667,840 (padded)
#define WS_BUCK    29667840    // bucketed [NCAP] uint2 -> 45,683,200
#define WS_CSRCOL  45683200    // csr_col [NCAP] i32 -> 53,690,880
#define WS_CSRW    53690880    // csr_w [NCAP*2] u32 -> 69,706,240

typedef __attribute__((ext_vector_type(8))) short bfrag;   // 8 bf16 (4 VGPRs)
typedef __attribute__((ext_vector_type(4))) float ffrag;   // 4 f32 acc

static __device__ __forceinline__ unsigned short f2bf(float f) {
    union { float f; unsigned int u; } v; v.f = f;
    unsigned int u = v.u;
    return (unsigned short)((u + 0x7fffu + ((u >> 16) & 1u)) >> 16);  // RNE
}
static __device__ __forceinline__ float bf_lo(unsigned int u) { return __uint_as_float(u << 16); }
static __device__ __forceinline__ float bf_hi(unsigned int u) { return __uint_as_float(u & 0xffff0000u); }

// ---- fuse Wlin@Wconv -> WallB (packed B-frag bf16); cbias; init gcursor ----
__global__ void k_fuse(const float* __restrict__ Wlin, const float* __restrict__ Wconv,
                       const float* __restrict__ blin, unsigned short* __restrict__ WallB,
                       float* __restrict__ cbias, int* __restrict__ gcursor) {
    int tid = blockIdx.x * 256 + threadIdx.x;
    if (tid < 16384) {
        int k = tid >> 12;
        int rem = tid & 4095;
        int f = rem >> 5;          // k-index in GEMM (0..127)
        int q = rem & 31;
        float a = 0.f;
        for (int pp = 0; pp < 32; pp++)
            a += Wlin[(k * 128 + f) * 32 + pp] * Wconv[(k * 32 + pp) * 32 + q];
        int col = k * 32 + q;      // n-index (0..127)
        int ntile = col >> 4, n15 = col & 15;
        int kstep = f >> 5, kl = f & 31;
        int lane = (kl >> 3) * 16 + n15;
        int j = kl & 7;
        WallB[(((ntile * 4 + kstep) * 64 + lane) << 3) + j] = f2bf(a);
    } else if (tid < 16512) {
        int i = tid - 16384;
        int k = i >> 5;
        int q = i & 31;
        float a = 0.f;
        for (int pp = 0; pp < 32; pp++)
            a += blin[k * 32 + pp] * Wconv[(k * 32 + pp) * 32 + q];
        cbias[k * 32 + q] = a;
    } else if (tid - 16512 < NB) {
        gcursor[tid - 16512] = (tid - 16512) * CAP;
    }
}

// ---- c[N,128] = bf16(x @ Wall + cbias) via MFMA;  p[N,8] = x @ aW1 (epilogue) ----
#define XLD 136   // bf16 elements per LDS row (16B-aligned frag reads)
__global__ __launch_bounds__(256) void k_cgemm(const float* __restrict__ x,
                                               const unsigned short* __restrict__ WallB,
                                               const float* __restrict__ cbias,
                                               const float* __restrict__ aW1,
                                               unsigned short* __restrict__ c,
                                               float* __restrict__ p) {
    __shared__ unsigned short xs[64 * XLD];   // 17,408 B (bf16 x-tile)
    __shared__ float aT[8 * 132];             // 4,224 B
    int t = threadIdx.x;
    int row0 = blockIdx.x * 64;
    int wv = t >> 6;
    int lane = t & 63;

    // stage aW1 transposed (fp32)
    for (int i = t; i < 1024; i += 256) {
        int j = i >> 7;
        int f = i & 127;
        float v = (j < 4) ? aW1[f * 4 + j] : aW1[512 + f * 4 + (j - 4)];
        aT[j * 132 + f] = v;
    }

    // stage 64 x-rows -> bf16 LDS
    const float4* xg = (const float4*)(x + (size_t)row0 * 128);
    for (int i = 0; i < 8; i++) {
        int idx = i * 256 + t;           // float4 index, 0..2047
        int r = idx >> 5;
        int cc = idx & 31;
        float4 v = make_float4(0.f, 0.f, 0.f, 0.f);
        if (row0 + r < N_NODES) v = xg[idx];
        ushort4 o;
        o.x = f2bf(v.x); o.y = f2bf(v.y); o.z = f2bf(v.z); o.w = f2bf(v.w);
        *(ushort4*)(xs + r * XLD + cc * 4) = o;
    }
    __syncthreads();

    // B fragments: wave wv owns cols [wv*32, wv*32+32) -> ntiles wv*2, wv*2+1
    bfrag B[2][4];
    #pragma unroll
    for (int nn = 0; nn < 2; nn++)
        #pragma unroll
        for (int ks = 0; ks < 4; ks++)
            B[nn][ks] = *(const bfrag*)(WallB + ((((wv * 2 + nn) * 4 + ks) * 64 + lane) << 3));

    ffrag acc[4][2];
    #pragma unroll
    for (int m = 0; m < 4; m++)
        #pragma unroll
        for (int nn = 0; nn < 2; nn++)
            acc[m][nn] = (ffrag){0.f, 0.f, 0.f, 0.f};

    int mrow = lane & 15;
    int koff = (lane >> 4) * 8;

    #pragma unroll
    for (int ks = 0; ks < 4; ks++) {
        bfrag A[4];
        #pragma unroll
        for (int m = 0; m < 4; m++)
            A[m] = *(const bfrag*)(xs + (m * 16 + mrow) * XLD + ks * 32 + koff);
        #pragma unroll
        for (int m = 0; m < 4; m++)
            #pragma unroll
            for (int nn = 0; nn < 2; nn++)
                acc[m][nn] = __builtin_amdgcn_mfma_f32_16x16x32_bf16(A[m], B[nn][ks], acc[m][nn], 0, 0, 0);
    }

    // epilogue: D[row = mtile*16 + quad*4 + r][col = wv*32 + nn*16 + (lane&15)]
    int quad = lane >> 4;
    int coln = lane & 15;
    #pragma unroll
    for (int nn = 0; nn < 2; nn++) {
        int col = wv * 32 + nn * 16 + coln;
        float cb = cbias[col];
        #pragma unroll
        for (int m = 0; m < 4; m++) {
            #pragma unroll
            for (int r = 0; r < 4; r++) {
                int row = row0 + m * 16 + quad * 4 + r;
                if (row < N_NODES)
                    c[(size_t)row * 128 + col] = f2bf(acc[m][nn][r] + cb);
            }
        }
    }

    // p epilogue (bf16 xs)
    int j = t & 7;
    const float* arow = aT + j * 132;
    for (int pass = 0; pass < 2; pass++) {
        int r = (t >> 3) + pass * 32;
        const unsigned int* xrow = (const unsigned int*)(xs + r * XLD);
        float accp = 0.f;
        #pragma unroll 8
        for (int f2 = 0; f2 < 64; f2++) {
            unsigned int u = xrow[f2];
            accp += bf_lo(u) * arow[2 * f2] + bf_hi(u) * arow[2 * f2 + 1];
        }
        int row = row0 + r;
        if (row < N_NODES) p[(size_t)row * 8 + j] = accp;
    }
}

// ---- bucket scatter (512 thr): LDS-reorder tile by bucket, claim runs, copy out ----
__global__ __launch_bounds__(512) void k_bucket_scatter(const int* __restrict__ erow,
                                                        const int* __restrict__ ecol,
                                                        int* __restrict__ gcursor,
                                                        uint2* __restrict__ bucketed) {
    __shared__ int lcnt[NB];
    __shared__ int lstart[NB];
    __shared__ int lcur[NB];
    __shared__ int gbase[NB];
    __shared__ uint2 buf[TILE_E];
    int t = threadIdx.x;
    int tile = blockIdx.x;
    int base = tile * TILE_E;
    int cnt = N_EDGES - base; if (cnt > TILE_E) cnt = TILE_E;

    for (int i = t; i < NB; i += 512) lcnt[i] = 0;
    __syncthreads();

    int rows[TILE_E / 512], cols[TILE_E / 512];
    #pragma unroll
    for (int i = 0; i < TILE_E / 512; i++) {
        int e = base + i * 512 + t;
        if (e < N_EDGES) {
            rows[i] = erow[e];
            cols[i] = ecol[e];
            atomicAdd(&lcnt[rows[i] >> BSH], 1);
        } else rows[i] = -1;
    }
    __syncthreads();

    if (t < 64) {
        int carry = 0;
        for (int ck = 0; ck < (NB + 63) / 64; ck++) {
            int i = ck * 64 + t;
            int v = (i < NB) ? lcnt[i] : 0;
            int s = v;
            #pragma unroll
            for (int d = 1; d < 64; d <<= 1) {
                int u = __shfl_up(s, d);
                if (t >= d) s += u;
            }
            int excl = s - v + carry;
            if (i < NB) { lstart[i] = excl; lcur[i] = excl; }
            carry += __shfl(s, 63);
        }
    } else {
        for (int i = t - 64; i < NB; i += 448)
            gbase[i] = atomicAdd(&gcursor[i], lcnt[i]);
    }
    __syncthreads();

    #pragma unroll
    for (int i = 0; i < TILE_E / 512; i++) {
        if (rows[i] >= 0) {
            int b = rows[i] >> BSH;
            int pos = atomicAdd(&lcur[b], 1);
            buf[pos] = make_uint2((unsigned)rows[i], (unsigned)cols[i]);
        }
    }
    __syncthreads();

    for (int jj = t; jj < cnt; jj += 512) {
        uint2 pr = buf[jj];
        int b = (int)pr.x >> BSH;
        int gpos = gbase[b] + (jj - lstart[b]);
        bucketed[gpos] = pr;
    }
}

// ---- fused CSR build: one block per 256-row bucket (1024 thr) ----
// pass 1: LDS histogram of the bucket's rows (cold read of the 40-80KB window)
// scan:   256-bin exclusive scan -> row_start/row_end globals + LDS bases
// pass 2: re-read window (L2-hot), softmax weights, LDS-claimed row-sorted
//         scatter into csr_col/csr_w (writes stay inside the bucket window)
__global__ __launch_bounds__(1024) void k_build(const uint2* __restrict__ bucketed,
                                                const int* __restrict__ gcursor,
                                                const float* __restrict__ p,
                                                const float* __restrict__ aW2,
                                                const float* __restrict__ ab1,
                                                const float* __restrict__ ab2,
                                                int* __restrict__ row_start,
                                                int* __restrict__ row_end,
                                                int* __restrict__ csr_col,
                                                unsigned int* __restrict__ csr_w) {
    __shared__ int hist[256];
    __shared__ int rstart[256];
    __shared__ int rcur[256];
    __shared__ float prr[256][4];
    __shared__ int wtot[4];
    __shared__ float sab1[4], sab2[4], saW2[16];

    int t = threadIdx.x;
    int b = blockIdx.x;
    int bstart = b * CAP;
    int bend = gcursor[b];
    int row0 = b << BSH;

    if (t < 256) {
        hist[t] = 0; rcur[t] = 0;
        int n = row0 + t;
        float4 pv = make_float4(0.f, 0.f, 0.f, 0.f);
        if (n < N_NODES) pv = *(const float4*)(p + (size_t)n * 8 + 4);
        *(float4*)prr[t] = pv;
    } else if (t < 260) sab1[t - 256] = ab1[t - 256];
    else if (t < 264) sab2[t - 260] = ab2[t - 260];
    else if (t < 280) saW2[t - 264] = aW2[t - 264];
    __syncthreads();

    // pass 1: histogram
    const int* brow = (const int*)bucketed;
    for (int i = bstart + t; i < bend; i += 1024)
        atomicAdd(&hist[brow[(size_t)i * 2] - row0], 1);
    __syncthreads();

    // 256-bin exclusive scan (waves 0-3)
    if (t < 256) {
        int v = hist[t];
        int s = v;
        #pragma unroll
        for (int d = 1; d < 64; d <<= 1) {
            int u = __shfl_up(s, d);
            if ((t & 63) >= d) s += u;
        }
        rstart[t] = s - v;                  // wave-local exclusive
        if ((t & 63) == 63) wtot[t >> 6] = s;
    }
    __syncthreads();
    if (t < 256) {
        int add = bstart;
        for (int w = 0; w < (t >> 6); w++) add += wtot[w];
        int st = rstart[t] + add;
        rstart[t] = st;
        int n = row0 + t;
        if (n < N_NODES) { row_start[n] = st; row_end[n] = st + hist[t]; }
    }
    __syncthreads();

    // pass 2: softmax + row-sorted scatter (window is L2-hot)
    for (int i = bstart + t; i < bend; i += 1024) {
        uint2 rc = bucketed[i];
        int rl = (int)rc.x - row0;
        int cl = (int)rc.y;
        float4 pc = *(const float4*)(p + (size_t)cl * 8);
        float h0 = pc.x + prr[rl][0] + sab1[0];
        float h1 = pc.y + prr[rl][1] + sab1[1];
        float h2 = pc.z + prr[rl][2] + sab1[2];
        float h3 = pc.w + prr[rl][3] + sab1[3];
        float sc[4];
        #pragma unroll
        for (int jq = 0; jq < 4; jq++)
            sc[jq] = h0 * saW2[jq] + h1 * saW2[4 + jq] + h2 * saW2[8 + jq]
                   + h3 * saW2[12 + jq] + sab2[jq];
        float m = fmaxf(fmaxf(sc[0], sc[1]), fmaxf(sc[2], sc[3]));
        float e0 = expf(sc[0] - m), e1 = expf(sc[1] - m);
        float e2 = expf(sc[2] - m), e3 = expf(sc[3] - m);
        float inv = 1.f / (e0 + e1 + e2 + e3);
        unsigned int w01 = (unsigned int)f2bf(e0 * inv) | ((unsigned int)f2bf(e1 * inv) << 16);
        unsigned int w23 = (unsigned int)f2bf(e2 * inv) | ((unsigned int)f2bf(e3 * inv) << 16);
        int pos = rstart[rl] + atomicAdd(&rcur[rl], 1);
        csr_col[pos] = cl;
        *(uint2*)(csr_w + (size_t)pos * 2) = make_uint2(w01, w23);
    }
}

// ---- aggregation: one wave per node; register-preloaded col/w segment + ----
// ---- shfl-broadcast addresses -> dependency-free batched gathers ----
template<int M, bool MASKED>
static __device__ __forceinline__ void agg_chunk(const unsigned int* __restrict__ c4,
                                                 int q, int cnt, int colv, unsigned int wvv,
                                                 int pair5, int lane, int wshl,
                                                 float& acc0, float& acc1) {
    unsigned int u[M], wq[M], addr[M];
    #pragma unroll
    for (int k = 0; k < M; k++) {
        int qq = q + k;
        bool val = !MASKED || (qq < cnt);
        int srcl = (val ? qq : q) | pair5;
        int cq = __shfl(colv, srcl);
        unsigned int ww = (unsigned int)__shfl((int)wvv, srcl);
        wq[k] = val ? ww : 0u;
        addr[k] = ((unsigned int)cq << 6) | (unsigned int)lane;
    }
    #pragma unroll
    for (int k = 0; k < M; k++) u[k] = c4[addr[k]];
    #pragma unroll
    for (int k = 0; k < M; k++) {
        float w = __uint_as_float((wq[k] << wshl) & 0xffff0000u);
        acc0 += w * bf_lo(u[k]);
        acc1 += w * bf_hi(u[k]);
    }
}

__global__ __launch_bounds__(256, 8) void k_agg(const int* __restrict__ csr_col,
                                                const unsigned int* __restrict__ csr_w,
                                                const unsigned int* __restrict__ c4,
                                                const int* __restrict__ row_start,
                                                const int* __restrict__ row_end,
                                                const float* __restrict__ bch,
                                                const float* __restrict__ Wcls,
                                                const float* __restrict__ bcls,
                                                float* __restrict__ out) {
    int n = (blockIdx.x * 256 + threadIdx.x) >> 6;
    int lane = threadIdx.x & 63;
    if (n >= N_NODES) return;
    int ch = lane >> 4;              // channel of both features 2*lane, 2*lane+1
    int pair5 = lane & 32;           // 0 -> w01 holder lanes, 32 -> w23 holder lanes
    int wshl = (ch & 1) ? 0 : 16;    // even channel sits in low half -> <<16
    int f0 = 2 * lane, f1 = 2 * lane + 1;

    int start = __builtin_amdgcn_readfirstlane(row_start[n]);
    int end = __builtin_amdgcn_readfirstlane(row_end[n]);

    float acc0 = 0.f, acc1 = 0.f;

    for (int s0 = start; s0 < end; s0 += 32) {
        int cnt = end - s0; if (cnt > 32) cnt = 32;
        // preload segment: lane e (mod 32) holds col of edge s0+e (both halves);
        // lanes 0-31 hold w01 word, lanes 32-63 hold w23 word of the same edge
        int e = s0 + (lane & 31);
        int ec = (e < end) ? e : (end - 1);
        int colv = csr_col[ec];
        unsigned int wvv = csr_w[((size_t)ec << 1) + (lane >> 5)];

        int q = 0;
        for (; q + 8 <= cnt; q += 8)
            agg_chunk<8, false>(c4, q, cnt, colv, wvv, pair5, lane, wshl, acc0, acc1);
        int rem = cnt - q;
        if (rem > 4)
            agg_chunk<8, true>(c4, q, cnt, colv, wvv, pair5, lane, wshl, acc0, acc1);
        else if (rem > 0)
            agg_chunk<4, true>(c4, q, cnt, colv, wvv, pair5, lane, wshl, acc0, acc1);
    }

    float v0 = acc0 + bch[f0];
    float v1 = acc1 + bch[f1];

    // per-channel L2 norm: channel = 16 consecutive lanes
    float ss = v0 * v0 + v1 * v1;
    #pragma unroll
    for (int m = 1; m <= 8; m <<= 1) ss += __shfl_xor(ss, m);
    float inv = 1.f / fmaxf(sqrtf(ss), 1e-12f);
    v0 *= inv;
    v1 *= inv;

    *(float2*)(out + (size_t)n * 128 + f0) = make_float2(v0, v1);

    float pl = v0 * Wcls[f0] + v1 * Wcls[f1];
    #pragma unroll
    for (int m = 1; m <= 32; m <<= 1) pl += __shfl_xor(pl, m);
    if (lane == 0) out[(size_t)N_NODES * 128 + n] = pl + bcls[0];
}

extern "C" void kernel_launch(void* const* d_in, const int* in_sizes, int n_in,
                              void* d_out, int out_size, void* d_ws, size_t ws_size,
                              hipStream_t stream) {
    const float* x    = (const float*)d_in[0];
    const int*   erow = (const int*)d_in[1];
    const int*   ecol = (const int*)d_in[2];
    const float* aW1  = (const float*)d_in[3];
    const float* ab1  = (const float*)d_in[4];
    const float* aW2  = (const float*)d_in[5];
    const float* ab2  = (const float*)d_in[6];
    const float* Wlin = (const float*)d_in[7];
    const float* blin = (const float*)d_in[8];
    const float* Wconv= (const float*)d_in[9];
    const float* bch  = (const float*)d_in[10];
    const float* Wcls = (const float*)d_in[11];
    const float* bcls = (const float*)d_in[12];
    float* out = (float*)d_out;

    char* ws = (char*)d_ws;
    unsigned short* WallB   = (unsigned short*)(ws + WS_WALLB);
    float*          cbias   = (float*)(ws + WS_CBIAS);
    float*          p       = (float*)(ws + WS_P);
    unsigned short* c       = (unsigned short*)(ws + WS_C);
    int*            rstart  = (int*)(ws + WS_RS);
    int*            rend    = (int*)(ws + WS_RE);
    int*            gcursor = (int*)(ws + WS_CUR);
    uint2*          bucketed= (uint2*)(ws + WS_BUCK);
    int*            csr_col = (int*)(ws + WS_CSRCOL);
    unsigned int*   csr_w   = (unsigned int*)(ws + WS_CSRW);

    k_fuse<<<67, 256, 0, stream>>>(Wlin, Wconv, blin, WallB, cbias, gcursor);
    k_cgemm<<<(N_NODES + 63) / 64, 256, 0, stream>>>(x, WallB, cbias, aW1, c, p);
    k_bucket_scatter<<<T_TILES, 512, 0, stream>>>(erow, ecol, gcursor, bucketed);
    k_build<<<NB, 1024, 0, stream>>>(bucketed, gcursor, p, aW2, ab1, ab2,
                                     rstart, rend, csr_col, csr_w);
    k_agg<<<(N_NODES * 64 + 255) / 256, 256, 0, stream>>>(csr_col, csr_w, (const unsigned int*)c,
                                                          rstart, rend, bch, Wcls, bcls, out);
}

// Round 8
// 253.384 us; speedup vs baseline: 1.5353x; 1.0358x over previous
//
#include <hip/hip_runtime.h>
#include <hip/hip_bf16.h>

#define N_NODES 100000
#define N_EDGES 1600000
#define NFEAT 128
#define PCD 32
#define KCH 4

#define TILE_E 4096
#define T_TILES 391            // ceil(N_EDGES / TILE_E)
#define BSH 8
#define NB 391                 // ceil(N_NODES / 256)
#define CAP 5120               // per-bucket capacity (mean 4096, +16 sigma)
#define NCAP (NB * CAP)        // 2,001,920

// ---------------- workspace layout (bytes) ----------------
#define WS_WALLB   0           // WallB packed bf16 [9][4][64][8] -> 36,864
#define WS_CBIAS   65536       // cbias [128] f32 -> 66,048
#define WS_P       66048       // p [N*8] f32 -> 3,266,048
#define WS_C       3266048     // c [N*128] bf16 -> 28,866,048
#define WS_RS      28866048    // row_start [N] i32 -> 29,266,048
#define WS_RE      29266048    // row_end [N] i32 -> 29,666,048
#define WS_CUR     29666048    // gcursor [NB] i32 -> 29,667,840 (padded)
#define WS_BUCK    29667840    // bucketed [NCAP] uint2 -> 45,683,200
#define WS_CSRCOL  45683200    // csr_col [NCAP] i32 -> 53,690,880
#define WS_CSRW    53690880    // csr_w [NCAP*2] u32 -> 69,706,240

typedef __attribute__((ext_vector_type(8))) short bfrag;   // 8 bf16 (4 VGPRs)
typedef __attribute__((ext_vector_type(4))) float ffrag;   // 4 f32 acc

static __device__ __forceinline__ unsigned short f2bf(float f) {
    union { float f; unsigned int u; } v; v.f = f;
    unsigned int u = v.u;
    return (unsigned short)((u + 0x7fffu + ((u >> 16) & 1u)) >> 16);  // RNE
}
static __device__ __forceinline__ float bf_lo(unsigned int u) { return __uint_as_float(u << 16); }
static __device__ __forceinline__ float bf_hi(unsigned int u) { return __uint_as_float(u & 0xffff0000u); }

// ---- fuse Wlin@Wconv -> WallB ntiles 0..7; aW1 -> ntile 8; cbias; gcursor ----
__global__ void k_fuse(const float* __restrict__ Wlin, const float* __restrict__ Wconv,
                       const float* __restrict__ blin, const float* __restrict__ aW1,
                       unsigned short* __restrict__ WallB,
                       float* __restrict__ cbias, int* __restrict__ gcursor) {
    int tid = blockIdx.x * 256 + threadIdx.x;
    if (tid < 16384) {
        int k = tid >> 12;
        int rem = tid & 4095;
        int f = rem >> 5;          // k-index in GEMM (0..127)
        int q = rem & 31;
        float a = 0.f;
        for (int pp = 0; pp < 32; pp++)
            a += Wlin[(k * 128 + f) * 32 + pp] * Wconv[(k * 32 + pp) * 32 + q];
        int col = k * 32 + q;      // n-index (0..127)
        int ntile = col >> 4, n15 = col & 15;
        int kstep = f >> 5, kl = f & 31;
        int lane = (kl >> 3) * 16 + n15;
        int j = kl & 7;
        WallB[(((ntile * 4 + kstep) * 64 + lane) << 3) + j] = f2bf(a);
    } else if (tid < 18432) {
        // ntile 8: rearranged aW1 (128 x 8), zero-padded to 16 cols
        int idx = tid - 16384;     // 0..2047
        int f = idx & 127;
        int col16 = idx >> 7;      // 0..15
        float a = 0.f;
        if (col16 < 4) a = aW1[f * 4 + col16];
        else if (col16 < 8) a = aW1[512 + f * 4 + (col16 - 4)];
        int kstep = f >> 5, kl = f & 31;
        int lane = (kl >> 3) * 16 + col16;
        int j = kl & 7;
        WallB[(((8 * 4 + kstep) * 64 + lane) << 3) + j] = f2bf(a);
    } else if (tid < 18560) {
        int i = tid - 18432;
        int k = i >> 5;
        int q = i & 31;
        float a = 0.f;
        for (int pp = 0; pp < 32; pp++)
            a += blin[k * 32 + pp] * Wconv[(k * 32 + pp) * 32 + q];
        cbias[k * 32 + q] = a;
    } else if (tid - 18560 < NB) {
        gcursor[tid - 18560] = (tid - 18560) * CAP;
    }
}

// ---- c[N,128] = bf16(x @ Wall + cbias);  p[N,8] = x @ aW1 — both via MFMA ----
#define XLD 136   // bf16 elements per LDS row (16B-aligned frag reads)
__global__ __launch_bounds__(256) void k_cgemm(const float* __restrict__ x,
                                               const unsigned short* __restrict__ WallB,
                                               const float* __restrict__ cbias,
                                               unsigned short* __restrict__ c,
                                               float* __restrict__ p) {
    __shared__ unsigned short xs[64 * XLD];   // 17,408 B (bf16 x-tile)
    int t = threadIdx.x;
    int row0 = blockIdx.x * 64;
    int wv = t >> 6;
    int lane = t & 63;

    // stage 64 x-rows -> bf16 LDS
    const float4* xg = (const float4*)(x + (size_t)row0 * 128);
    for (int i = 0; i < 8; i++) {
        int idx = i * 256 + t;           // float4 index, 0..2047
        int r = idx >> 5;
        int cc = idx & 31;
        float4 v = make_float4(0.f, 0.f, 0.f, 0.f);
        if (row0 + r < N_NODES) v = xg[idx];
        ushort4 o;
        o.x = f2bf(v.x); o.y = f2bf(v.y); o.z = f2bf(v.z); o.w = f2bf(v.w);
        *(ushort4*)(xs + r * XLD + cc * 4) = o;
    }
    __syncthreads();

    // B fragments: wave wv owns cols [wv*32, wv*32+32) -> ntiles wv*2, wv*2+1
    bfrag B[2][4];
    #pragma unroll
    for (int nn = 0; nn < 2; nn++)
        #pragma unroll
        for (int ks = 0; ks < 4; ks++)
            B[nn][ks] = *(const bfrag*)(WallB + ((((wv * 2 + nn) * 4 + ks) * 64 + lane) << 3));

    ffrag acc[4][2];
    #pragma unroll
    for (int m = 0; m < 4; m++)
        #pragma unroll
        for (int nn = 0; nn < 2; nn++)
            acc[m][nn] = (ffrag){0.f, 0.f, 0.f, 0.f};

    int mrow = lane & 15;
    int koff = (lane >> 4) * 8;

    #pragma unroll
    for (int ks = 0; ks < 4; ks++) {
        bfrag A[4];
        #pragma unroll
        for (int m = 0; m < 4; m++)
            A[m] = *(const bfrag*)(xs + (m * 16 + mrow) * XLD + ks * 32 + koff);
        #pragma unroll
        for (int m = 0; m < 4; m++)
            #pragma unroll
            for (int nn = 0; nn < 2; nn++)
                acc[m][nn] = __builtin_amdgcn_mfma_f32_16x16x32_bf16(A[m], B[nn][ks], acc[m][nn], 0, 0, 0);
    }

    // p-tile: wave wv computes rows [wv*16, wv*16+16) x cols 0..7 via ntile 8
    ffrag accp = (ffrag){0.f, 0.f, 0.f, 0.f};
    #pragma unroll
    for (int ks = 0; ks < 4; ks++) {
        bfrag B9 = *(const bfrag*)(WallB + (((32 + ks) * 64 + lane) << 3));
        bfrag A = *(const bfrag*)(xs + (wv * 16 + mrow) * XLD + ks * 32 + koff);
        accp = __builtin_amdgcn_mfma_f32_16x16x32_bf16(A, B9, accp, 0, 0, 0);
    }

    // epilogue: D[row = mtile*16 + quad*4 + r][col = wv*32 + nn*16 + (lane&15)]
    int quad = lane >> 4;
    int coln = lane & 15;
    #pragma unroll
    for (int nn = 0; nn < 2; nn++) {
        int col = wv * 32 + nn * 16 + coln;
        float cb = cbias[col];
        #pragma unroll
        for (int m = 0; m < 4; m++) {
            #pragma unroll
            for (int r = 0; r < 4; r++) {
                int row = row0 + m * 16 + quad * 4 + r;
                if (row < N_NODES)
                    c[(size_t)row * 128 + col] = f2bf(acc[m][nn][r] + cb);
            }
        }
    }

    // p epilogue (coln<8 lanes carry valid columns)
    if (coln < 8) {
        #pragma unroll
        for (int r = 0; r < 4; r++) {
            int row = row0 + wv * 16 + quad * 4 + r;
            if (row < N_NODES) p[(size_t)row * 8 + coln] = accp[r];
        }
    }
}

// ---- bucket scatter (512 thr): LDS-reorder tile by bucket, claim runs, copy out ----
__global__ __launch_bounds__(512) void k_bucket_scatter(const int* __restrict__ erow,
                                                        const int* __restrict__ ecol,
                                                        int* __restrict__ gcursor,
                                                        uint2* __restrict__ bucketed) {
    __shared__ int lcnt[NB];
    __shared__ int lstart[NB];
    __shared__ int lcur[NB];
    __shared__ int gbase[NB];
    __shared__ uint2 buf[TILE_E];
    int t = threadIdx.x;
    int tile = blockIdx.x;
    int base = tile * TILE_E;
    int cnt = N_EDGES - base; if (cnt > TILE_E) cnt = TILE_E;

    for (int i = t; i < NB; i += 512) lcnt[i] = 0;
    __syncthreads();

    int rows[TILE_E / 512], cols[TILE_E / 512];
    #pragma unroll
    for (int i = 0; i < TILE_E / 512; i++) {
        int e = base + i * 512 + t;
        if (e < N_EDGES) {
            rows[i] = erow[e];
            cols[i] = ecol[e];
            atomicAdd(&lcnt[rows[i] >> BSH], 1);
        } else rows[i] = -1;
    }
    __syncthreads();

    if (t < 64) {
        int carry = 0;
        for (int ck = 0; ck < (NB + 63) / 64; ck++) {
            int i = ck * 64 + t;
            int v = (i < NB) ? lcnt[i] : 0;
            int s = v;
            #pragma unroll
            for (int d = 1; d < 64; d <<= 1) {
                int u = __shfl_up(s, d);
                if (t >= d) s += u;
            }
            int excl = s - v + carry;
            if (i < NB) { lstart[i] = excl; lcur[i] = excl; }
            carry += __shfl(s, 63);
        }
    } else {
        for (int i = t - 64; i < NB; i += 448)
            gbase[i] = atomicAdd(&gcursor[i], lcnt[i]);
    }
    __syncthreads();

    #pragma unroll
    for (int i = 0; i < TILE_E / 512; i++) {
        if (rows[i] >= 0) {
            int b = rows[i] >> BSH;
            int pos = atomicAdd(&lcur[b], 1);
            buf[pos] = make_uint2((unsigned)rows[i], (unsigned)cols[i]);
        }
    }
    __syncthreads();

    for (int jj = t; jj < cnt; jj += 512) {
        uint2 pr = buf[jj];
        int b = (int)pr.x >> BSH;
        int gpos = gbase[b] + (jj - lstart[b]);
        bucketed[gpos] = pr;
    }
}

// ---- fused CSR build: one block per 256-row bucket (1024 thr) ----
__global__ __launch_bounds__(1024) void k_build(const uint2* __restrict__ bucketed,
                                                const int* __restrict__ gcursor,
                                                const float* __restrict__ p,
                                                const float* __restrict__ aW2,
                                                const float* __restrict__ ab1,
                                                const float* __restrict__ ab2,
                                                int* __restrict__ row_start,
                                                int* __restrict__ row_end,
                                                int* __restrict__ csr_col,
                                                unsigned int* __restrict__ csr_w) {
    __shared__ int hist[256];
    __shared__ int rstart[256];
    __shared__ int rcur[256];
    __shared__ float prr[256][4];
    __shared__ int wtot[4];
    __shared__ float sab1[4], sab2[4], saW2[16];

    int t = threadIdx.x;
    int b = blockIdx.x;
    int bstart = b * CAP;
    int bend = gcursor[b];
    int row0 = b << BSH;

    if (t < 256) {
        hist[t] = 0; rcur[t] = 0;
        int n = row0 + t;
        float4 pv = make_float4(0.f, 0.f, 0.f, 0.f);
        if (n < N_NODES) pv = *(const float4*)(p + (size_t)n * 8 + 4);
        *(float4*)prr[t] = pv;
    } else if (t < 260) sab1[t - 256] = ab1[t - 256];
    else if (t < 264) sab2[t - 260] = ab2[t - 260];
    else if (t < 280) saW2[t - 264] = aW2[t - 264];
    __syncthreads();

    // pass 1: histogram
    const int* brow = (const int*)bucketed;
    for (int i = bstart + t; i < bend; i += 1024)
        atomicAdd(&hist[brow[(size_t)i * 2] - row0], 1);
    __syncthreads();

    // 256-bin exclusive scan (waves 0-3)
    if (t < 256) {
        int v = hist[t];
        int s = v;
        #pragma unroll
        for (int d = 1; d < 64; d <<= 1) {
            int u = __shfl_up(s, d);
            if ((t & 63) >= d) s += u;
        }
        rstart[t] = s - v;                  // wave-local exclusive
        if ((t & 63) == 63) wtot[t >> 6] = s;
    }
    __syncthreads();
    if (t < 256) {
        int add = bstart;
        for (int w = 0; w < (t >> 6); w++) add += wtot[w];
        int st = rstart[t] + add;
        rstart[t] = st;
        int n = row0 + t;
        if (n < N_NODES) { row_start[n] = st; row_end[n] = st + hist[t]; }
    }
    __syncthreads();

    // pass 2: softmax + row-sorted scatter (window is L2-hot)
    for (int i = bstart + t; i < bend; i += 1024) {
        uint2 rc = bucketed[i];
        int rl = (int)rc.x - row0;
        int cl = (int)rc.y;
        float4 pc = *(const float4*)(p + (size_t)cl * 8);
        float h0 = pc.x + prr[rl][0] + sab1[0];
        float h1 = pc.y + prr[rl][1] + sab1[1];
        float h2 = pc.z + prr[rl][2] + sab1[2];
        float h3 = pc.w + prr[rl][3] + sab1[3];
        float sc[4];
        #pragma unroll
        for (int jq = 0; jq < 4; jq++)
            sc[jq] = h0 * saW2[jq] + h1 * saW2[4 + jq] + h2 * saW2[8 + jq]
                   + h3 * saW2[12 + jq] + sab2[jq];
        float m = fmaxf(fmaxf(sc[0], sc[1]), fmaxf(sc[2], sc[3]));
        float e0 = expf(sc[0] - m), e1 = expf(sc[1] - m);
        float e2 = expf(sc[2] - m), e3 = expf(sc[3] - m);
        float inv = 1.f / (e0 + e1 + e2 + e3);
        unsigned int w01 = (unsigned int)f2bf(e0 * inv) | ((unsigned int)f2bf(e1 * inv) << 16);
        unsigned int w23 = (unsigned int)f2bf(e2 * inv) | ((unsigned int)f2bf(e3 * inv) << 16);
        int pos = rstart[rl] + atomicAdd(&rcur[rl], 1);
        csr_col[pos] = cl;
        *(uint2*)(csr_w + (size_t)pos * 2) = make_uint2(w01, w23);
    }
}

// ---- aggregation: one wave per node; register-preloaded col/w segment + ----
// ---- shfl-broadcast addresses -> dependency-free batched gathers ----
template<int M, bool MASKED>
static __device__ __forceinline__ void agg_chunk(const unsigned int* __restrict__ c4,
                                                 int q, int cnt, int colv, unsigned int wvv,
                                                 int pair5, int lane, int wshl,
                                                 float& acc0, float& acc1) {
    unsigned int u[M], wq[M], addr[M];
    #pragma unroll
    for (int k = 0; k < M; k++) {
        int qq = q + k;
        bool val = !MASKED || (qq < cnt);
        int srcl = (val ? qq : q) | pair5;
        int cq = __shfl(colv, srcl);
        unsigned int ww = (unsigned int)__shfl((int)wvv, srcl);
        wq[k] = val ? ww : 0u;
        addr[k] = ((unsigned int)cq << 6) | (unsigned int)lane;
    }
    #pragma unroll
    for (int k = 0; k < M; k++) u[k] = c4[addr[k]];
    #pragma unroll
    for (int k = 0; k < M; k++) {
        float w = __uint_as_float((wq[k] << wshl) & 0xffff0000u);
        acc0 += w * bf_lo(u[k]);
        acc1 += w * bf_hi(u[k]);
    }
}

__global__ __launch_bounds__(256, 8) void k_agg(const int* __restrict__ csr_col,
                                                const unsigned int* __restrict__ csr_w,
                                                const unsigned int* __restrict__ c4,
                                                const int* __restrict__ row_start,
                                                const int* __restrict__ row_end,
                                                const float* __restrict__ bch,
                                                const float* __restrict__ Wcls,
                                                const float* __restrict__ bcls,
                                                float* __restrict__ out) {
    int n = (blockIdx.x * 256 + threadIdx.x) >> 6;
    int lane = threadIdx.x & 63;
    if (n >= N_NODES) return;
    int ch = lane >> 4;              // channel of both features 2*lane, 2*lane+1
    int pair5 = lane & 32;           // 0 -> w01 holder lanes, 32 -> w23 holder lanes
    int wshl = (ch & 1) ? 0 : 16;    // even channel sits in low half -> <<16
    int f0 = 2 * lane, f1 = 2 * lane + 1;

    int start = __builtin_amdgcn_readfirstlane(row_start[n]);
    int end = __builtin_amdgcn_readfirstlane(row_end[n]);

    float acc0 = 0.f, acc1 = 0.f;

    for (int s0 = start; s0 < end; s0 += 32) {
        int cnt = end - s0; if (cnt > 32) cnt = 32;
        // preload segment: lane e (mod 32) holds col of edge s0+e (both halves);
        // lanes 0-31 hold w01 word, lanes 32-63 hold w23 word of the same edge
        int e = s0 + (lane & 31);
        int ec = (e < end) ? e : (end - 1);
        int colv = csr_col[ec];
        unsigned int wvv = csr_w[((size_t)ec << 1) + (lane >> 5)];

        int q = 0;
        for (; q + 8 <= cnt; q += 8)
            agg_chunk<8, false>(c4, q, cnt, colv, wvv, pair5, lane, wshl, acc0, acc1);
        int rem = cnt - q;
        if (rem > 4)
            agg_chunk<8, true>(c4, q, cnt, colv, wvv, pair5, lane, wshl, acc0, acc1);
        else if (rem > 0)
            agg_chunk<4, true>(c4, q, cnt, colv, wvv, pair5, lane, wshl, acc0, acc1);
    }

    float v0 = acc0 + bch[f0];
    float v1 = acc1 + bch[f1];

    // per-channel L2 norm: channel = 16 consecutive lanes
    float ss = v0 * v0 + v1 * v1;
    #pragma unroll
    for (int m = 1; m <= 8; m <<= 1) ss += __shfl_xor(ss, m);
    float inv = 1.f / fmaxf(sqrtf(ss), 1e-12f);
    v0 *= inv;
    v1 *= inv;

    *(float2*)(out + (size_t)n * 128 + f0) = make_float2(v0, v1);

    float pl = v0 * Wcls[f0] + v1 * Wcls[f1];
    #pragma unroll
    for (int m = 1; m <= 32; m <<= 1) pl += __shfl_xor(pl, m);
    if (lane == 0) out[(size_t)N_NODES * 128 + n] = pl + bcls[0];
}

extern "C" void kernel_launch(void* const* d_in, const int* in_sizes, int n_in,
                              void* d_out, int out_size, void* d_ws, size_t ws_size,
                              hipStream_t stream) {
    const float* x    = (const float*)d_in[0];
    const int*   erow = (const int*)d_in[1];
    const int*   ecol = (const int*)d_in[2];
    const float* aW1  = (const float*)d_in[3];
    const float* ab1  = (const float*)d_in[4];
    const float* aW2  = (const float*)d_in[5];
    const float* ab2  = (const float*)d_in[6];
    const float* Wlin = (const float*)d_in[7];
    const float* blin = (const float*)d_in[8];
    const float* Wconv= (const float*)d_in[9];
    const float* bch  = (const float*)d_in[10];
    const float* Wcls = (const float*)d_in[11];
    const float* bcls = (const float*)d_in[12];
    float* out = (float*)d_out;

    char* ws = (char*)d_ws;
    unsigned short* WallB   = (unsigned short*)(ws + WS_WALLB);
    float*          cbias   = (float*)(ws + WS_CBIAS);
    float*          p       = (float*)(ws + WS_P);
    unsigned short* c       = (unsigned short*)(ws + WS_C);
    int*            rstart  = (int*)(ws + WS_RS);
    int*            rend    = (int*)(ws + WS_RE);
    int*            gcursor = (int*)(ws + WS_CUR);
    uint2*          bucketed= (uint2*)(ws + WS_BUCK);
    int*            csr_col = (int*)(ws + WS_CSRCOL);
    unsigned int*   csr_w   = (unsigned int*)(ws + WS_CSRW);

    k_fuse<<<75, 256, 0, stream>>>(Wlin, Wconv, blin, aW1, WallB, cbias, gcursor);
    k_cgemm<<<(N_NODES + 63) / 64, 256, 0, stream>>>(x, WallB, cbias, c, p);
    k_bucket_scatter<<<T_TILES, 512, 0, stream>>>(erow, ecol, gcursor, bucketed);
    k_build<<<NB, 1024, 0, stream>>>(bucketed, gcursor, p, aW2, ab1, ab2,
                                     rstart, rend, csr_col, csr_w);
    k_agg<<<(N_NODES * 64 + 255) / 256, 256, 0, stream>>>(csr_col, csr_w, (const unsigned int*)c,
                                                          rstart, rend, bch, Wcls, bcls, out);
}

// Round 9
// 244.698 us; speedup vs baseline: 1.5898x; 1.0355x over previous
//
#include <hip/hip_runtime.h>
#include <hip/hip_bf16.h>

#define N_NODES 100000
#define N_EDGES 1600000
#define NFEAT 128
#define PCD 32
#define KCH 4

#define TILE_E 4096
#define T_TILES 391            // ceil(N_EDGES / TILE_E)
#define BSH 8
#define NB 391                 // ceil(N_NODES / 256)
#define CAP 5120               // per-bucket capacity (mean 4096, +16 sigma)
#define NCAP (NB * CAP)        // 2,001,920

#define CGB 782                // cgemm pair-blocks (2 tiles each -> 1564 tiles)
#define FATB (CGB + T_TILES)   // 1173 fat blocks

// ---------------- workspace layout (bytes) ----------------
#define WS_WALLB   0           // WallB packed bf16 [9][4][64][8] -> 36,864
#define WS_CBIAS   65536       // cbias [128] f32 -> 66,048
#define WS_P       66048       // p [N*8] f32 -> 3,266,048
#define WS_C       3266048     // c [N*128] bf16 -> 28,866,048
#define WS_RS      28866048    // row_start [N] i32 -> 29,266,048
#define WS_RE      29266048    // row_end [N] i32 -> 29,666,048
#define WS_CUR     29666048    // gcursor [NB] i32 -> 29,667,840 (padded)
#define WS_BUCK    29667840    // bucketed [NCAP] uint2 -> 45,683,200
#define WS_CSRCOL  45683200    // csr_col [NCAP] i32 -> 53,690,880
#define WS_CSRW    53690880    // csr_w [NCAP*2] u32 -> 69,706,240

typedef __attribute__((ext_vector_type(8))) short bfrag;   // 8 bf16 (4 VGPRs)
typedef __attribute__((ext_vector_type(4))) float ffrag;   // 4 f32 acc

static __device__ __forceinline__ unsigned short f2bf(float f) {
    union { float f; unsigned int u; } v; v.f = f;
    unsigned int u = v.u;
    return (unsigned short)((u + 0x7fffu + ((u >> 16) & 1u)) >> 16);  // RNE
}
static __device__ __forceinline__ float bf_lo(unsigned int u) { return __uint_as_float(u << 16); }
static __device__ __forceinline__ float bf_hi(unsigned int u) { return __uint_as_float(u & 0xffff0000u); }

// ---- fuse Wlin@Wconv -> WallB ntiles 0..7; aW1 -> ntile 8; cbias; gcursor ----
__global__ void k_fuse(const float* __restrict__ Wlin, const float* __restrict__ Wconv,
                       const float* __restrict__ blin, const float* __restrict__ aW1,
                       unsigned short* __restrict__ WallB,
                       float* __restrict__ cbias, int* __restrict__ gcursor) {
    int tid = blockIdx.x * 256 + threadIdx.x;
    if (tid < 16384) {
        int k = tid >> 12;
        int rem = tid & 4095;
        int f = rem >> 5;          // k-index in GEMM (0..127)
        int q = rem & 31;
        float a = 0.f;
        for (int pp = 0; pp < 32; pp++)
            a += Wlin[(k * 128 + f) * 32 + pp] * Wconv[(k * 32 + pp) * 32 + q];
        int col = k * 32 + q;      // n-index (0..127)
        int ntile = col >> 4, n15 = col & 15;
        int kstep = f >> 5, kl = f & 31;
        int lane = (kl >> 3) * 16 + n15;
        int j = kl & 7;
        WallB[(((ntile * 4 + kstep) * 64 + lane) << 3) + j] = f2bf(a);
    } else if (tid < 18432) {
        // ntile 8: rearranged aW1 (128 x 8), zero-padded to 16 cols
        int idx = tid - 16384;     // 0..2047
        int f = idx & 127;
        int col16 = idx >> 7;      // 0..15
        float a = 0.f;
        if (col16 < 4) a = aW1[f * 4 + col16];
        else if (col16 < 8) a = aW1[512 + f * 4 + (col16 - 4)];
        int kstep = f >> 5, kl = f & 31;
        int lane = (kl >> 3) * 16 + col16;
        int j = kl & 7;
        WallB[(((8 * 4 + kstep) * 64 + lane) << 3) + j] = f2bf(a);
    } else if (tid < 18560) {
        int i = tid - 18432;
        int k = i >> 5;
        int q = i & 31;
        float a = 0.f;
        for (int pp = 0; pp < 32; pp++)
            a += blin[k * 32 + pp] * Wconv[(k * 32 + pp) * 32 + q];
        cbias[k * 32 + q] = a;
    } else if (tid - 18560 < NB) {
        gcursor[tid - 18560] = (tid - 18560) * CAP;
    }
}

#define XLD 136   // bf16 elements per LDS row (16B-aligned frag reads)

union SharedU {
    struct { unsigned short xs[2][64 * XLD]; } cg;                       // 34,816 B
    struct { int lcnt[NB], lstart[NB], lcur[NB], gbase[NB];
             uint2 buf[TILE_E]; } sc;                                    // 39,024 B
};

// ---- FAT kernel: blocks [0,CGB) = 2x cgemm tiles; [CGB,FATB) = bucket_scatter ----
// cgemm: c[N,128] = bf16(x @ Wall + cbias); p[N,8] = x @ aW1 (both MFMA).
// bucket_scatter: LDS-reorder a 4096-edge tile by 256-row bucket, claim runs,
// copy out to the gapped bucketed array. The two halves are data-independent
// and co-resident per CU -> MFMA/VMEM work overlaps LDS-atomic work.
__global__ __launch_bounds__(512) void k_cgsc(const float* __restrict__ x,
                                              const unsigned short* __restrict__ WallB,
                                              const float* __restrict__ cbias,
                                              unsigned short* __restrict__ c,
                                              float* __restrict__ p,
                                              const int* __restrict__ erow,
                                              const int* __restrict__ ecol,
                                              int* __restrict__ gcursor,
                                              uint2* __restrict__ bucketed) {
    __shared__ SharedU sh;

    if (blockIdx.x < CGB) {
        // ---------------- cgemm half: two 64-row tiles per block ----------------
        int t512 = threadIdx.x;
        int half = t512 >> 8;                  // which tile of the pair
        int t = t512 & 255;
        int tile = blockIdx.x * 2 + half;      // 0..1563
        int row0 = tile * 64;
        unsigned short* xs = sh.cg.xs[half];
        int wv = t >> 6;                       // 0..3 within tile
        int lane = t & 63;

        // stage 64 x-rows -> bf16 LDS
        const float4* xg = (const float4*)(x + (size_t)row0 * 128);
        for (int i = 0; i < 8; i++) {
            int idx = i * 256 + t;             // float4 index, 0..2047
            int r = idx >> 5;
            int cc = idx & 31;
            float4 v = make_float4(0.f, 0.f, 0.f, 0.f);
            if (row0 + r < N_NODES) v = xg[idx];
            ushort4 o;
            o.x = f2bf(v.x); o.y = f2bf(v.y); o.z = f2bf(v.z); o.w = f2bf(v.w);
            *(ushort4*)(xs + r * XLD + cc * 4) = o;
        }
        __syncthreads();

        // B fragments: wave wv owns cols [wv*32, wv*32+32)
        bfrag B[2][4];
        #pragma unroll
        for (int nn = 0; nn < 2; nn++)
            #pragma unroll
            for (int ks = 0; ks < 4; ks++)
                B[nn][ks] = *(const bfrag*)(WallB + ((((wv * 2 + nn) * 4 + ks) * 64 + lane) << 3));

        ffrag acc[4][2];
        #pragma unroll
        for (int m = 0; m < 4; m++)
            #pragma unroll
            for (int nn = 0; nn < 2; nn++)
                acc[m][nn] = (ffrag){0.f, 0.f, 0.f, 0.f};

        int mrow = lane & 15;
        int koff = (lane >> 4) * 8;

        #pragma unroll
        for (int ks = 0; ks < 4; ks++) {
            bfrag A[4];
            #pragma unroll
            for (int m = 0; m < 4; m++)
                A[m] = *(const bfrag*)(xs + (m * 16 + mrow) * XLD + ks * 32 + koff);
            #pragma unroll
            for (int m = 0; m < 4; m++)
                #pragma unroll
                for (int nn = 0; nn < 2; nn++)
                    acc[m][nn] = __builtin_amdgcn_mfma_f32_16x16x32_bf16(A[m], B[nn][ks], acc[m][nn], 0, 0, 0);
        }

        // p-tile: wave wv computes rows [wv*16, wv*16+16) x cols 0..7 via ntile 8
        ffrag accp = (ffrag){0.f, 0.f, 0.f, 0.f};
        #pragma unroll
        for (int ks = 0; ks < 4; ks++) {
            bfrag B9 = *(const bfrag*)(WallB + (((32 + ks) * 64 + lane) << 3));
            bfrag A = *(const bfrag*)(xs + (wv * 16 + mrow) * XLD + ks * 32 + koff);
            accp = __builtin_amdgcn_mfma_f32_16x16x32_bf16(A, B9, accp, 0, 0, 0);
        }

        // epilogue: D[row = mtile*16 + quad*4 + r][col = wv*32 + nn*16 + (lane&15)]
        int quad = lane >> 4;
        int coln = lane & 15;
        #pragma unroll
        for (int nn = 0; nn < 2; nn++) {
            int col = wv * 32 + nn * 16 + coln;
            float cb = cbias[col];
            #pragma unroll
            for (int m = 0; m < 4; m++) {
                #pragma unroll
                for (int r = 0; r < 4; r++) {
                    int row = row0 + m * 16 + quad * 4 + r;
                    if (row < N_NODES)
                        c[(size_t)row * 128 + col] = f2bf(acc[m][nn][r] + cb);
                }
            }
        }

        // p epilogue (coln<8 lanes carry valid columns)
        if (coln < 8) {
            #pragma unroll
            for (int r = 0; r < 4; r++) {
                int row = row0 + wv * 16 + quad * 4 + r;
                if (row < N_NODES) p[(size_t)row * 8 + coln] = accp[r];
            }
        }
    } else {
        // ---------------- bucket_scatter half (verbatim, 512 thr) ----------------
        int t = threadIdx.x;
        int tile = blockIdx.x - CGB;
        int base = tile * TILE_E;
        int cnt = N_EDGES - base; if (cnt > TILE_E) cnt = TILE_E;

        for (int i = t; i < NB; i += 512) sh.sc.lcnt[i] = 0;
        __syncthreads();

        int rows[TILE_E / 512], cols[TILE_E / 512];
        #pragma unroll
        for (int i = 0; i < TILE_E / 512; i++) {
            int e = base + i * 512 + t;
            if (e < N_EDGES) {
                rows[i] = erow[e];
                cols[i] = ecol[e];
                atomicAdd(&sh.sc.lcnt[rows[i] >> BSH], 1);
            } else rows[i] = -1;
        }
        __syncthreads();

        if (t < 64) {
            int carry = 0;
            for (int ck = 0; ck < (NB + 63) / 64; ck++) {
                int i = ck * 64 + t;
                int v = (i < NB) ? sh.sc.lcnt[i] : 0;
                int s = v;
                #pragma unroll
                for (int d = 1; d < 64; d <<= 1) {
                    int u = __shfl_up(s, d);
                    if (t >= d) s += u;
                }
                int excl = s - v + carry;
                if (i < NB) { sh.sc.lstart[i] = excl; sh.sc.lcur[i] = excl; }
                carry += __shfl(s, 63);
            }
        } else {
            for (int i = t - 64; i < NB; i += 448)
                sh.sc.gbase[i] = atomicAdd(&gcursor[i], sh.sc.lcnt[i]);
        }
        __syncthreads();

        #pragma unroll
        for (int i = 0; i < TILE_E / 512; i++) {
            if (rows[i] >= 0) {
                int b = rows[i] >> BSH;
                int pos = atomicAdd(&sh.sc.lcur[b], 1);
                sh.sc.buf[pos] = make_uint2((unsigned)rows[i], (unsigned)cols[i]);
            }
        }
        __syncthreads();

        for (int jj = t; jj < cnt; jj += 512) {
            uint2 pr = sh.sc.buf[jj];
            int b = (int)pr.x >> BSH;
            int gpos = sh.sc.gbase[b] + (jj - sh.sc.lstart[b]);
            bucketed[gpos] = pr;
        }
    }
}

// ---- fused CSR build: one block per 256-row bucket (1024 thr) ----
__global__ __launch_bounds__(1024) void k_build(const uint2* __restrict__ bucketed,
                                                const int* __restrict__ gcursor,
                                                const float* __restrict__ p,
                                                const float* __restrict__ aW2,
                                                const float* __restrict__ ab1,
                                                const float* __restrict__ ab2,
                                                int* __restrict__ row_start,
                                                int* __restrict__ row_end,
                                                int* __restrict__ csr_col,
                                                unsigned int* __restrict__ csr_w) {
    __shared__ int hist[256];
    __shared__ int rstart[256];
    __shared__ int rcur[256];
    __shared__ float prr[256][4];
    __shared__ int wtot[4];
    __shared__ float sab1[4], sab2[4], saW2[16];

    int t = threadIdx.x;
    int b = blockIdx.x;
    int bstart = b * CAP;
    int bend = gcursor[b];
    int row0 = b << BSH;

    if (t < 256) {
        hist[t] = 0; rcur[t] = 0;
        int n = row0 + t;
        float4 pv = make_float4(0.f, 0.f, 0.f, 0.f);
        if (n < N_NODES) pv = *(const float4*)(p + (size_t)n * 8 + 4);
        *(float4*)prr[t] = pv;
    } else if (t < 260) sab1[t - 256] = ab1[t - 256];
    else if (t < 264) sab2[t - 260] = ab2[t - 260];
    else if (t < 280) saW2[t - 264] = aW2[t - 264];
    __syncthreads();

    // pass 1: histogram
    const int* brow = (const int*)bucketed;
    for (int i = bstart + t; i < bend; i += 1024)
        atomicAdd(&hist[brow[(size_t)i * 2] - row0], 1);
    __syncthreads();

    // 256-bin exclusive scan (waves 0-3)
    if (t < 256) {
        int v = hist[t];
        int s = v;
        #pragma unroll
        for (int d = 1; d < 64; d <<= 1) {
            int u = __shfl_up(s, d);
            if ((t & 63) >= d) s += u;
        }
        rstart[t] = s - v;                  // wave-local exclusive
        if ((t & 63) == 63) wtot[t >> 6] = s;
    }
    __syncthreads();
    if (t < 256) {
        int add = bstart;
        for (int w = 0; w < (t >> 6); w++) add += wtot[w];
        int st = rstart[t] + add;
        rstart[t] = st;
        int n = row0 + t;
        if (n < N_NODES) { row_start[n] = st; row_end[n] = st + hist[t]; }
    }
    __syncthreads();

    // pass 2: softmax + row-sorted scatter (window is L2-hot)
    for (int i = bstart + t; i < bend; i += 1024) {
        uint2 rc = bucketed[i];
        int rl = (int)rc.x - row0;
        int cl = (int)rc.y;
        float4 pc = *(const float4*)(p + (size_t)cl * 8);
        float h0 = pc.x + prr[rl][0] + sab1[0];
        float h1 = pc.y + prr[rl][1] + sab1[1];
        float h2 = pc.z + prr[rl][2] + sab1[2];
        float h3 = pc.w + prr[rl][3] + sab1[3];
        float sc[4];
        #pragma unroll
        for (int jq = 0; jq < 4; jq++)
            sc[jq] = h0 * saW2[jq] + h1 * saW2[4 + jq] + h2 * saW2[8 + jq]
                   + h3 * saW2[12 + jq] + sab2[jq];
        float m = fmaxf(fmaxf(sc[0], sc[1]), fmaxf(sc[2], sc[3]));
        float e0 = expf(sc[0] - m), e1 = expf(sc[1] - m);
        float e2 = expf(sc[2] - m), e3 = expf(sc[3] - m);
        float inv = 1.f / (e0 + e1 + e2 + e3);
        unsigned int w01 = (unsigned int)f2bf(e0 * inv) | ((unsigned int)f2bf(e1 * inv) << 16);
        unsigned int w23 = (unsigned int)f2bf(e2 * inv) | ((unsigned int)f2bf(e3 * inv) << 16);
        int pos = rstart[rl] + atomicAdd(&rcur[rl], 1);
        csr_col[pos] = cl;
        *(uint2*)(csr_w + (size_t)pos * 2) = make_uint2(w01, w23);
    }
}

// ---- aggregation: one wave per node; register-preloaded col/w segment + ----
// ---- shfl-broadcast addresses -> dependency-free batched gathers ----
template<int M, bool MASKED>
static __device__ __forceinline__ void agg_chunk(const unsigned int* __restrict__ c4,
                                                 int q, int cnt, int colv, unsigned int wvv,
                                                 int pair5, int lane, int wshl,
                                                 float& acc0, float& acc1) {
    unsigned int u[M], wq[M], addr[M];
    #pragma unroll
    for (int k = 0; k < M; k++) {
        int qq = q + k;
        bool val = !MASKED || (qq < cnt);
        int srcl = (val ? qq : q) | pair5;
        int cq = __shfl(colv, srcl);
        unsigned int ww = (unsigned int)__shfl((int)wvv, srcl);
        wq[k] = val ? ww : 0u;
        addr[k] = ((unsigned int)cq << 6) | (unsigned int)lane;
    }
    #pragma unroll
    for (int k = 0; k < M; k++) u[k] = c4[addr[k]];
    #pragma unroll
    for (int k = 0; k < M; k++) {
        float w = __uint_as_float((wq[k] << wshl) & 0xffff0000u);
        acc0 += w * bf_lo(u[k]);
        acc1 += w * bf_hi(u[k]);
    }
}

__global__ __launch_bounds__(256, 8) void k_agg(const int* __restrict__ csr_col,
                                                const unsigned int* __restrict__ csr_w,
                                                const unsigned int* __restrict__ c4,
                                                const int* __restrict__ row_start,
                                                const int* __restrict__ row_end,
                                                const float* __restrict__ bch,
                                                const float* __restrict__ Wcls,
                                                const float* __restrict__ bcls,
                                                float* __restrict__ out) {
    int n = (blockIdx.x * 256 + threadIdx.x) >> 6;
    int lane = threadIdx.x & 63;
    if (n >= N_NODES) return;
    int ch = lane >> 4;              // channel of both features 2*lane, 2*lane+1
    int pair5 = lane & 32;           // 0 -> w01 holder lanes, 32 -> w23 holder lanes
    int wshl = (ch & 1) ? 0 : 16;    // even channel sits in low half -> <<16
    int f0 = 2 * lane, f1 = 2 * lane + 1;

    int start = __builtin_amdgcn_readfirstlane(row_start[n]);
    int end = __builtin_amdgcn_readfirstlane(row_end[n]);

    float acc0 = 0.f, acc1 = 0.f;

    for (int s0 = start; s0 < end; s0 += 32) {
        int cnt = end - s0; if (cnt > 32) cnt = 32;
        // preload segment: lane e (mod 32) holds col of edge s0+e (both halves);
        // lanes 0-31 hold w01 word, lanes 32-63 hold w23 word of the same edge
        int e = s0 + (lane & 31);
        int ec = (e < end) ? e : (end - 1);
        int colv = csr_col[ec];
        unsigned int wvv = csr_w[((size_t)ec << 1) + (lane >> 5)];

        int q = 0;
        for (; q + 8 <= cnt; q += 8)
            agg_chunk<8, false>(c4, q, cnt, colv, wvv, pair5, lane, wshl, acc0, acc1);
        int rem = cnt - q;
        if (rem > 4)
            agg_chunk<8, true>(c4, q, cnt, colv, wvv, pair5, lane, wshl, acc0, acc1);
        else if (rem > 0)
            agg_chunk<4, true>(c4, q, cnt, colv, wvv, pair5, lane, wshl, acc0, acc1);
    }

    float v0 = acc0 + bch[f0];
    float v1 = acc1 + bch[f1];

    // per-channel L2 norm: channel = 16 consecutive lanes
    float ss = v0 * v0 + v1 * v1;
    #pragma unroll
    for (int m = 1; m <= 8; m <<= 1) ss += __shfl_xor(ss, m);
    float inv = 1.f / fmaxf(sqrtf(ss), 1e-12f);
    v0 *= inv;
    v1 *= inv;

    *(float2*)(out + (size_t)n * 128 + f0) = make_float2(v0, v1);

    float pl = v0 * Wcls[f0] + v1 * Wcls[f1];
    #pragma unroll
    for (int m = 1; m <= 32; m <<= 1) pl += __shfl_xor(pl, m);
    if (lane == 0) out[(size_t)N_NODES * 128 + n] = pl + bcls[0];
}

extern "C" void kernel_launch(void* const* d_in, const int* in_sizes, int n_in,
                              void* d_out, int out_size, void* d_ws, size_t ws_size,
                              hipStream_t stream) {
    const float* x    = (const float*)d_in[0];
    const int*   erow = (const int*)d_in[1];
    const int*   ecol = (const int*)d_in[2];
    const float* aW1  = (const float*)d_in[3];
    const float* ab1  = (const float*)d_in[4];
    const float* aW2  = (const float*)d_in[5];
    const float* ab2  = (const float*)d_in[6];
    const float* Wlin = (const float*)d_in[7];
    const float* blin = (const float*)d_in[8];
    const float* Wconv= (const float*)d_in[9];
    const float* bch  = (const float*)d_in[10];
    const float* Wcls = (const float*)d_in[11];
    const float* bcls = (const float*)d_in[12];
    float* out = (float*)d_out;

    char* ws = (char*)d_ws;
    unsigned short* WallB   = (unsigned short*)(ws + WS_WALLB);
    float*          cbias   = (float*)(ws + WS_CBIAS);
    float*          p       = (float*)(ws + WS_P);
    unsigned short* c       = (unsigned short*)(ws + WS_C);
    int*            rstart  = (int*)(ws + WS_RS);
    int*            rend    = (int*)(ws + WS_RE);
    int*            gcursor = (int*)(ws + WS_CUR);
    uint2*          bucketed= (uint2*)(ws + WS_BUCK);
    int*            csr_col = (int*)(ws + WS_CSRCOL);
    unsigned int*   csr_w   = (unsigned int*)(ws + WS_CSRW);

    k_fuse<<<75, 256, 0, stream>>>(Wlin, Wconv, blin, aW1, WallB, cbias, gcursor);
    k_cgsc<<<FATB, 512, 0, stream>>>(x, WallB, cbias, c, p, erow, ecol, gcursor, bucketed);
    k_build<<<NB, 1024, 0, stream>>>(bucketed, gcursor, p, aW2, ab1, ab2,
                                     rstart, rend, csr_col, csr_w);
    k_agg<<<(N_NODES * 64 + 255) / 256, 256, 0, stream>>>(csr_col, csr_w, (const unsigned int*)c,
                                                          rstart, rend, bch, Wcls, bcls, out);
}